// Round 1
// baseline (497.417 us; speedup 1.0000x reference)
//
#include <hip/hip_runtime.h>
#include <hip/hip_bf16.h>

#define NB 16
#define DIM 256
#define HW 4096
#define HEADS 4
#define DHEAD 32
#define MEM 4
#define HIDDEN 128
#define OQKV 384

typedef __hip_bfloat16 bf16;

// ---- ws layout (bytes) ----
constexpr size_t OFF_R    = 0;                        // 65536 f32
constexpr size_t OFF_W1   = OFF_R + 65536*4;          // 98304 f32
constexpr size_t OFF_RMAX = OFF_W1 + 98304*4;         // 2048 f32
constexpr size_t OFF_RSUM = OFF_RMAX + 2048*4;        // 2048 f32
constexpr size_t OFF_PCTX = OFF_RSUM + 2048*4;        // 8*64*1024 f32 = 2MB
constexpr size_t OFF_M    = OFF_PCTX + 8*64*1024*4;   // 16*256*128 bf16 = 1MB
constexpr size_t OFF_QKV  = OFF_M + (size_t)NB*DIM*HIDDEN*2; // 16*384*4096 bf16 ~50MB

// K1: per-position inverse-RMS scale r = sqrt(256)/max(||x||,1e-12)
__global__ void k_rms1(const float* __restrict__ x, float* __restrict__ r) {
    int idx = blockIdx.x * 256 + threadIdx.x;   // b*HW + n, 65536 total
    int b = idx >> 12, n = idx & 4095;
    const float* p = x + (size_t)b * DIM * HW + n;
    float s = 0.f;
#pragma unroll 8
    for (int c = 0; c < DIM; ++c) { float v = p[(size_t)c * HW]; s += v * v; }
    r[idx] = 16.0f / fmaxf(sqrtf(s), 1e-12f);
}

// K2: w1 = w_qkv * g1 (broadcast over rows)
__global__ void k_prep(const float* __restrict__ wqkv, const float* __restrict__ g1,
                       float* __restrict__ w1) {
    int i = blockIdx.x * 256 + threadIdx.x;     // 98304
    w1[i] = wqkv[i] * g1[i & (DIM - 1)];
}

// K3: qkv[b] = (w1 @ x[b]) * r[b,:]   (384x256 @ 256x4096), bf16 out
__global__ __launch_bounds__(256) void k_qkv(const float* __restrict__ w1,
                                             const float* __restrict__ x,
                                             const float* __restrict__ r,
                                             bf16* __restrict__ qkv) {
    int nt = blockIdx.x, mt = blockIdx.y, b = blockIdx.z;
    __shared__ float As[64][65];
    __shared__ float Bs[64][65];
    int t = threadIdx.x;
    int tx = t & 15, ty = t >> 4;
    float acc[4][4] = {};
    const float* xb = x + (size_t)b * DIM * HW;
    for (int kk = 0; kk < DIM; kk += 64) {
#pragma unroll
        for (int j = 0; j < 16; ++j) {
            int e = t + j * 256; int ar = e >> 6, ac = e & 63;
            As[ar][ac] = w1[(mt * 64 + ar) * DIM + kk + ac];
            Bs[ar][ac] = xb[(size_t)(kk + ar) * HW + nt * 64 + ac];
        }
        __syncthreads();
#pragma unroll 8
        for (int k = 0; k < 64; ++k) {
            float a0 = As[ty*4+0][k], a1 = As[ty*4+1][k], a2 = As[ty*4+2][k], a3 = As[ty*4+3][k];
            float b0 = Bs[k][tx*4+0], b1 = Bs[k][tx*4+1], b2 = Bs[k][tx*4+2], b3 = Bs[k][tx*4+3];
            acc[0][0] += a0*b0; acc[0][1] += a0*b1; acc[0][2] += a0*b2; acc[0][3] += a0*b3;
            acc[1][0] += a1*b0; acc[1][1] += a1*b1; acc[1][2] += a1*b2; acc[1][3] += a1*b3;
            acc[2][0] += a2*b0; acc[2][1] += a2*b1; acc[2][2] += a2*b2; acc[2][3] += a2*b3;
            acc[3][0] += a3*b0; acc[3][1] += a3*b1; acc[3][2] += a3*b2; acc[3][3] += a3*b3;
        }
        __syncthreads();
    }
#pragma unroll
    for (int i = 0; i < 4; ++i)
#pragma unroll
        for (int j = 0; j < 4; ++j) {
            int row = mt * 64 + ty * 4 + i;
            int col = nt * 64 + tx * 4 + j;
            float val = acc[i][j] * r[b * HW + col];
            qkv[((size_t)b * OQKV + row) * HW + col] = __float2bfloat16(val);
        }
}

// K4: q softmax over DHEAD (in place), times attn_scale
__global__ void k_qsoft(bf16* __restrict__ qkv) {
    int idx = blockIdx.x * 256 + threadIdx.x;   // b*HEADS*HW, 262144
    int b = idx >> 14, rem = idx & 16383;
    int h = rem >> 12, n = rem & 4095;
    bf16* p = qkv + ((size_t)b * OQKV + h * DHEAD) * HW + n;
    float v[DHEAD]; float m = -1e30f;
#pragma unroll
    for (int d = 0; d < DHEAD; ++d) { v[d] = __bfloat162float(p[(size_t)d * HW]); m = fmaxf(m, v[d]); }
    float s = 0.f;
#pragma unroll
    for (int d = 0; d < DHEAD; ++d) { v[d] = __expf(v[d] - m); s += v[d]; }
    float inv = 0.17677669529663689f / s;       // attn_scale / sum
#pragma unroll
    for (int d = 0; d < DHEAD; ++d) p[(size_t)d * HW] = __float2bfloat16(v[d] * inv);
}

// K5a: k-row max & sum(exp) over 4100 (4 mem cols + 4096 spatial). one wave/row.
__global__ void k_kstats(const bf16* __restrict__ qkv, const float* __restrict__ memkv,
                         float* __restrict__ rowmax, float* __restrict__ rowsum) {
    int row = blockIdx.x * 4 + (threadIdx.x >> 6);  // 0..2047 = b*128 + h*32 + d
    int lane = threadIdx.x & 63;
    int b = row >> 7, hd = row & 127;
    const bf16* p = qkv + ((size_t)b * OQKV + HIDDEN + hd) * HW;
    float m = -1e30f;
    for (int n = lane; n < HW; n += 64) m = fmaxf(m, __bfloat162float(p[n]));
    if (lane < MEM) m = fmaxf(m, memkv[hd * MEM + lane]);
#pragma unroll
    for (int off = 32; off; off >>= 1) m = fmaxf(m, __shfl_xor(m, off));
    float s = 0.f;
    for (int n = lane; n < HW; n += 64) s += __expf(__bfloat162float(p[n]) - m);
    if (lane < MEM) s += __expf(memkv[hd * MEM + lane] - m);
#pragma unroll
    for (int off = 32; off; off >>= 1) s += __shfl_xor(s, off);
    if (lane == 0) { rowmax[row] = m; rowsum[row] = s; }
}

// K5b: partial context over a 512-column chunk. pctx[chunk][bh][d*32+e]
__global__ __launch_bounds__(256) void k_ctx(const bf16* __restrict__ qkv,
                                             const float* __restrict__ memkv,
                                             const float* __restrict__ rowmax,
                                             float* __restrict__ pctx) {
    int chunk = blockIdx.x, bh = blockIdx.y;
    int b = bh >> 2, h = bh & 3;
    int t = threadIdx.x;
    int d = t >> 3;
    int e0 = (t & 7) * 4;
    __shared__ float eks[32][65];
    __shared__ float vs[32][65];
    __shared__ float rmx[32];
    const bf16* kp = qkv + ((size_t)b * OQKV + HIDDEN + h * DHEAD) * HW;
    const bf16* vp = qkv + ((size_t)b * OQKV + 2 * HIDDEN + h * DHEAD) * HW;
    if (t < 32) rmx[t] = rowmax[bh * DHEAD + t];
    float acc[4] = {0.f, 0.f, 0.f, 0.f};
    for (int sc = 0; sc < 8; ++sc) {
        int n0 = chunk * 512 + sc * 64;
        __syncthreads();
#pragma unroll
        for (int j = 0; j < 8; ++j) {
            int e = t + j * 256; int rr = e >> 6, cc = e & 63;
            eks[rr][cc] = __expf(__bfloat162float(kp[(size_t)rr * HW + n0 + cc]) - rmx[rr]);
            vs[rr][cc]  = __bfloat162float(vp[(size_t)rr * HW + n0 + cc]);
        }
        __syncthreads();
#pragma unroll 8
        for (int n = 0; n < 64; ++n) {
            float ek = eks[d][n];
            acc[0] += ek * vs[e0 + 0][n];
            acc[1] += ek * vs[e0 + 1][n];
            acc[2] += ek * vs[e0 + 2][n];
            acc[3] += ek * vs[e0 + 3][n];
        }
    }
    if (chunk == 0) {   // memory-KV columns
#pragma unroll
        for (int m2 = 0; m2 < MEM; ++m2) {
            float ek = __expf(memkv[(h * DHEAD + d) * MEM + m2] - rmx[d]);
            acc[0] += ek * memkv[512 + (h * DHEAD + e0 + 0) * MEM + m2];
            acc[1] += ek * memkv[512 + (h * DHEAD + e0 + 1) * MEM + m2];
            acc[2] += ek * memkv[512 + (h * DHEAD + e0 + 2) * MEM + m2];
            acc[3] += ek * memkv[512 + (h * DHEAD + e0 + 3) * MEM + m2];
        }
    }
    float* o = pctx + ((size_t)chunk * 64 + bh) * 1024;
    o[d * 32 + e0 + 0] = acc[0];
    o[d * 32 + e0 + 1] = acc[1];
    o[d * 32 + e0 + 2] = acc[2];
    o[d * 32 + e0 + 3] = acc[3];
}

// K5c: reduce partials, normalize by rowsum, fold w_out: M[b][o][h*32+d]
__global__ void k_M(const float* __restrict__ pctx, const float* __restrict__ rowsum,
                    const float* __restrict__ wout, bf16* __restrict__ Mmat) {
    int b = blockIdx.x; int t = threadIdx.x;
    __shared__ float ctx[HEADS][DHEAD][DHEAD];
#pragma unroll
    for (int j = 0; j < 16; ++j) {
        int e = t + j * 256;                    // h*1024 + d*32 + ee
        int h = e >> 10, dd = (e >> 5) & 31, ee = e & 31;
        float s = 0.f;
#pragma unroll
        for (int c = 0; c < 8; ++c) s += pctx[((size_t)c * 64 + b * 4 + h) * 1024 + (e & 1023)];
        ctx[h][dd][ee] = s / rowsum[(b * 4 + h) * DHEAD + dd];
    }
    __syncthreads();
    int o = t;
    for (int hd = 0; hd < HIDDEN; ++hd) {
        int h = hd >> 5, dd = hd & 31;
        float s = 0.f;
#pragma unroll
        for (int e = 0; e < DHEAD; ++e) s += wout[o * HIDDEN + h * DHEAD + e] * ctx[h][dd][e];
        Mmat[((size_t)b * DIM + o) * HIDDEN + hd] = __float2bfloat16(s);
    }
}

// K6: pre[b] = M[b] @ q_soft[b] + b_out  (256x128 @ 128x4096), bf16 out into k/v scratch region
__global__ __launch_bounds__(256) void k_out(const bf16* __restrict__ Mmat,
                                             bf16* __restrict__ qkv,
                                             const float* __restrict__ bout) {
    int nt = blockIdx.x, mt = blockIdx.y, b = blockIdx.z;
    __shared__ bf16 Ms[128][130];
    __shared__ bf16 qs[128][66];
    int t = threadIdx.x;
    const bf16* Mb = Mmat + ((size_t)b * DIM + mt * 128) * HIDDEN;
#pragma unroll
    for (int j = 0; j < 64; ++j) {
        int e = t + j * 256;
        Ms[e >> 7][e & 127] = Mb[e];
    }
#pragma unroll
    for (int j = 0; j < 32; ++j) {
        int e = t + j * 256; int rr = e >> 6, cc = e & 63;
        qs[rr][cc] = qkv[((size_t)b * OQKV + rr) * HW + nt * 64 + cc];
    }
    __syncthreads();
    int tx = t & 15, ty = t >> 4;               // 16 col-groups x 16 row-groups
    float acc[8][4] = {};
#pragma unroll 4
    for (int k = 0; k < HIDDEN; ++k) {
        float q0 = __bfloat162float(qs[k][tx*4+0]);
        float q1 = __bfloat162float(qs[k][tx*4+1]);
        float q2 = __bfloat162float(qs[k][tx*4+2]);
        float q3 = __bfloat162float(qs[k][tx*4+3]);
#pragma unroll
        for (int i = 0; i < 8; ++i) {
            float a = __bfloat162float(Ms[ty*8+i][k]);
            acc[i][0] += a*q0; acc[i][1] += a*q1; acc[i][2] += a*q2; acc[i][3] += a*q3;
        }
    }
    bf16* pre = qkv + ((size_t)b * OQKV + HIDDEN) * HW;  // rows 128..383 reused
#pragma unroll
    for (int i = 0; i < 8; ++i) {
        int row = mt * 128 + ty * 8 + i;
        float bias = bout[row];
#pragma unroll
        for (int j = 0; j < 4; ++j) {
            int col = nt * 64 + tx * 4 + j;
            pre[(size_t)row * HW + col] = __float2bfloat16(acc[i][j] + bias);
        }
    }
}

// K7: final rmsnorm over channels, fp32 out
__global__ void k_rms2(const bf16* __restrict__ qkv, const float* __restrict__ g2,
                       float* __restrict__ out) {
    int idx = blockIdx.x * 256 + threadIdx.x;   // 65536
    int b = idx >> 12, n = idx & 4095;
    const bf16* p = qkv + ((size_t)b * OQKV + HIDDEN) * HW + n;
    float s = 0.f;
#pragma unroll 8
    for (int c = 0; c < DIM; ++c) { float v = __bfloat162float(p[(size_t)c * HW]); s += v * v; }
    float r2 = 16.0f / fmaxf(sqrtf(s), 1e-12f);
    float* po = out + (size_t)b * DIM * HW + n;
#pragma unroll 8
    for (int c = 0; c < DIM; ++c)
        po[(size_t)c * HW] = __bfloat162float(p[(size_t)c * HW]) * r2 * g2[c];
}

extern "C" void kernel_launch(void* const* d_in, const int* in_sizes, int n_in,
                              void* d_out, int out_size, void* d_ws, size_t ws_size,
                              hipStream_t stream) {
    const float* x     = (const float*)d_in[0];
    const float* g1    = (const float*)d_in[1];
    const float* wqkv  = (const float*)d_in[2];
    const float* memkv = (const float*)d_in[3];
    const float* wout  = (const float*)d_in[4];
    const float* bout  = (const float*)d_in[5];
    const float* g2    = (const float*)d_in[6];
    float* out = (float*)d_out;
    char* ws = (char*)d_ws;

    float* r    = (float*)(ws + OFF_R);
    float* w1   = (float*)(ws + OFF_W1);
    float* rmax = (float*)(ws + OFF_RMAX);
    float* rsum = (float*)(ws + OFF_RSUM);
    float* pctx = (float*)(ws + OFF_PCTX);
    bf16*  Mmat = (bf16*)(ws + OFF_M);
    bf16*  qkv  = (bf16*)(ws + OFF_QKV);

    k_rms1<<<256, 256, 0, stream>>>(x, r);
    k_prep<<<384, 256, 0, stream>>>(wqkv, g1, w1);
    k_qkv<<<dim3(64, 6, NB), 256, 0, stream>>>(w1, x, r, qkv);
    k_qsoft<<<1024, 256, 0, stream>>>(qkv);
    k_kstats<<<512, 256, 0, stream>>>(qkv, memkv, rmax, rsum);
    k_ctx<<<dim3(8, 64), 256, 0, stream>>>(qkv, memkv, rmax, pctx);
    k_M<<<NB, 256, 0, stream>>>(pctx, rsum, wout, Mmat);
    k_out<<<dim3(64, 2, NB), 256, 0, stream>>>(Mmat, qkv, bout);
    k_rms2<<<256, 256, 0, stream>>>(qkv, g2, out);
}

// Round 2
// 223.753 us; speedup vs baseline: 2.2231x; 2.2231x over previous
//
#include <hip/hip_runtime.h>
#include <hip/hip_bf16.h>

#define NB 16
#define DIM 256
#define HW 4096
#define HEADS 4
#define DHEAD 32
#define MEM 4
#define HIDDEN 128

typedef __hip_bfloat16 bf16;
typedef __attribute__((ext_vector_type(8))) short bf16x8;   // 8 bf16 = 4 VGPR (guide §3)
typedef __attribute__((ext_vector_type(4))) float f32x4;
typedef __attribute__((ext_vector_type(4))) unsigned short us4;

#define AS1 __attribute__((address_space(1)))
#define AS3 __attribute__((address_space(3)))

__device__ __forceinline__ void gld_lds16(const void* g, void* l) {
    __builtin_amdgcn_global_load_lds((const AS1 void*)g, (AS3 void*)l, 16, 0, 0);
}
__device__ __forceinline__ float b2f(short s) {
    union { unsigned int u; float f; } x; x.u = ((unsigned int)(unsigned short)s) << 16; return x.f;
}
__device__ __forceinline__ short f2bs(float f) {
    bf16 h = __float2bfloat16(f);
    return *reinterpret_cast<short*>(&h);
}

// ---- ws layout (bytes) ----
constexpr size_t OFF_W1B  = 0;                                   // 98304 bf16
constexpr size_t OFF_R    = OFF_W1B + 98304*2;                   // 65536 f32
constexpr size_t OFF_RP   = OFF_R + 65536*4;                     // 4*65536 f32
constexpr size_t OFF_RMAX = OFF_RP + 4*65536*4;                  // 2048 f32
constexpr size_t OFF_RSUM = OFF_RMAX + 2048*4;                   // 2048 f32
constexpr size_t OFF_PCTX = OFF_RSUM + 2048*4;                   // 8*64*1024 f32
constexpr size_t OFF_M    = OFF_PCTX + 8*64*1024*4;              // 16*256*128 bf16
constexpr size_t OFF_PSUM = OFF_M + (size_t)NB*DIM*HIDDEN*2;     // 2*65536 f32
constexpr size_t OFF_R2   = OFF_PSUM + 2*65536*4;                // 65536 f32
constexpr size_t OFF_QT   = OFF_R2 + 65536*4;                    // 16*4096*128 bf16 (~16.8MB)
constexpr size_t OFF_KV   = OFF_QT + (size_t)NB*HW*HIDDEN*2;     // 16*256*4096 bf16 (~33.6MB)
constexpr size_t OFF_XT   = OFF_KV + (size_t)NB*256*HW*2;        // 16*4096*256 bf16 (~33.6MB); reused as `pre` by k_out

// K1: w1b = bf16(w_qkv * g1)
__global__ void k_prep(const float* __restrict__ wqkv, const float* __restrict__ g1,
                       short* __restrict__ w1b) {
    int i = blockIdx.x * 256 + threadIdx.x;     // 98304
    w1b[i] = f2bs(wqkv[i] * g1[i & (DIM - 1)]);
}

// K2: transpose x -> xT[b][n][c] (bf16) + partial sumsq per (b,n) over 64-c stripe
__global__ __launch_bounds__(256) void k_tr(const float* __restrict__ x,
                                            short* __restrict__ xT,
                                            float* __restrict__ rpart) {
    int n0 = blockIdx.x * 64, cy = blockIdx.y, b = blockIdx.z;
    int c0 = cy * 64;
    __shared__ short xs[64 * 65];
    __shared__ float ps[4][64];
    int t = threadIdx.x;
    int ln = t & 63, cb = t >> 6;
    const float* xp = x + ((size_t)b * DIM + c0) * HW + n0;
    float ss = 0.f;
#pragma unroll
    for (int j = 0; j < 16; ++j) {
        int c = cb * 16 + j;
        float v = xp[(size_t)c * HW + ln];
        ss += v * v;
        xs[c * 65 + ln] = f2bs(v);
    }
    ps[cb][ln] = ss;
    __syncthreads();
    if (t < 64)
        rpart[((size_t)cy * NB + b) * HW + n0 + t] = ps[0][t] + ps[1][t] + ps[2][t] + ps[3][t];
    int n = t >> 2, ch = t & 3;
    short tmp[16];
#pragma unroll
    for (int i = 0; i < 16; ++i) tmp[i] = xs[(ch * 16 + i) * 65 + n];
    short* o = xT + ((size_t)b * HW + n0 + n) * DIM + c0 + ch * 16;
    *(bf16x8*)(o)     = *(bf16x8*)(tmp);
    *(bf16x8*)(o + 8) = *(bf16x8*)(tmp + 8);
}

// K3: r = 16 / max(||x||, eps)
__global__ void k_rfin(const float* __restrict__ rpart, float* __restrict__ r) {
    int i = blockIdx.x * 256 + threadIdx.x;
    float s = rpart[i] + rpart[65536 + i] + rpart[131072 + i] + rpart[196608 + i];
    r[i] = 16.0f / fmaxf(sqrtf(s), 1e-12f);
}

// K4: MFMA GEMM qkv = (w1b @ xT^T) * r.  mt==0 -> fused q-softmax -> qT[n][hd];
//     mt==1,2 -> k,v rows into kv buffer.
__global__ __launch_bounds__(256) void k_qkv(const short* __restrict__ w1b,
                                             const short* __restrict__ xT,
                                             const float* __restrict__ r,
                                             short* __restrict__ kv,
                                             short* __restrict__ qT) {
    int nt = blockIdx.x, mt = blockIdx.y, b = blockIdx.z;
    __shared__ short As[128 * 64];
    __shared__ short Bs[128 * 64];
    int t = threadIdx.x;
    int wave = t >> 6, lane = t & 63;
    int wr = wave >> 1, wc = wave & 1;
    int lr = lane & 15, lg = lane >> 4;
    const short* Ag = w1b + (size_t)mt * 128 * 256;
    const short* Bg = xT + ((size_t)b * HW + nt * 128) * 256;
    const f32x4 fz = {0.f, 0.f, 0.f, 0.f};
    f32x4 acc[4][4];
#pragma unroll
    for (int m = 0; m < 4; ++m)
#pragma unroll
        for (int n = 0; n < 4; ++n) acc[m][n] = fz;

    for (int kk = 0; kk < 256; kk += 64) {
        if (kk) __syncthreads();
#pragma unroll
        for (int is = 0; is < 4; ++is) {
            int o = is * 4096 + t * 16;          // byte offset, linear LDS dest
            int rr2 = o >> 7;                    // 128 B per row
            int js = ((o >> 4) & 7) ^ (rr2 & 7); // pre-swizzled global source (T2/m173)
            gld_lds16(Ag + (size_t)rr2 * 256 + kk + js * 8, (char*)As + o);
            gld_lds16(Bg + (size_t)rr2 * 256 + kk + js * 8, (char*)Bs + o);
        }
        __syncthreads();
#pragma unroll
        for (int ks = 0; ks < 2; ++ks) {
            bf16x8 av[4], bv[4];
            int j = lg + 4 * ks;
#pragma unroll
            for (int m = 0; m < 4; ++m) {
                int row = wr * 64 + m * 16 + lr;
                av[m] = *(const bf16x8*)((const char*)As + row * 128 + ((j ^ (row & 7)) << 4));
            }
#pragma unroll
            for (int n = 0; n < 4; ++n) {
                int row = wc * 64 + n * 16 + lr;
                bv[n] = *(const bf16x8*)((const char*)Bs + row * 128 + ((j ^ (row & 7)) << 4));
            }
#pragma unroll
            for (int m = 0; m < 4; ++m)
#pragma unroll
                for (int n = 0; n < 4; ++n)
                    acc[m][n] = __builtin_amdgcn_mfma_f32_16x16x32_bf16(av[m], bv[n], acc[m][n], 0, 0, 0);
        }
    }
    int gcol0 = nt * 128 + wc * 64 + lr;
    float rv[4];
#pragma unroll
    for (int n = 0; n < 4; ++n) rv[n] = r[(size_t)b * HW + gcol0 + n * 16];

    if (mt == 0) {
        // q: softmax over d (32 rows/head), scale, write qT[b][n][hd]
#pragma unroll
        for (int n = 0; n < 4; ++n) {
            int gcol = gcol0 + n * 16;
#pragma unroll
            for (int a = 0; a < 2; ++a) {
                float v[8];
#pragma unroll
                for (int mm = 0; mm < 2; ++mm)
#pragma unroll
                    for (int q = 0; q < 4; ++q)
                        v[mm * 4 + q] = acc[2 * a + mm][n][q] * rv[n];
                float mx = v[0];
#pragma unroll
                for (int i = 1; i < 8; ++i) mx = fmaxf(mx, v[i]);
                mx = fmaxf(mx, __shfl_xor(mx, 16));
                mx = fmaxf(mx, __shfl_xor(mx, 32));
                float sum = 0.f;
#pragma unroll
                for (int i = 0; i < 8; ++i) { v[i] = __expf(v[i] - mx); sum += v[i]; }
                sum += __shfl_xor(sum, 16);
                sum += __shfl_xor(sum, 32);
                float inv = 0.17677669529663689f / sum;   // dhead^-0.5 / sum
                size_t base = ((size_t)b * HW + gcol) * 128 + (wr * 2 + a) * 32 + lg * 4;
#pragma unroll
                for (int mm = 0; mm < 2; ++mm) {
                    us4 pk;
#pragma unroll
                    for (int q = 0; q < 4; ++q)
                        pk[q] = (unsigned short)f2bs(v[mm * 4 + q] * inv);
                    *(us4*)(qT + base + mm * 16) = pk;
                }
            }
        }
    } else {
        short* outp = kv + ((size_t)b * 256 + (mt - 1) * 128) * HW;
#pragma unroll
        for (int n = 0; n < 4; ++n) {
            int gcol = gcol0 + n * 16;
#pragma unroll
            for (int m = 0; m < 4; ++m)
#pragma unroll
                for (int q = 0; q < 4; ++q) {
                    int grow = wr * 64 + m * 16 + lg * 4 + q;
                    outp[(size_t)grow * HW + gcol] = f2bs(acc[m][n][q] * rv[n]);
                }
        }
    }
}

// K5: k-row max & sum(exp) over 4100 cols (4 mem + 4096 spatial)
__global__ void k_kstats(const short* __restrict__ kv, const float* __restrict__ memkv,
                         float* __restrict__ rowmax, float* __restrict__ rowsum) {
    int row = blockIdx.x * 4 + (threadIdx.x >> 6);  // b*128 + hd
    int lane = threadIdx.x & 63;
    int b = row >> 7, hd = row & 127;
    const short* p = kv + ((size_t)b * 256 + hd) * HW;
    float m = -1e30f;
    for (int n = lane; n < HW; n += 64) m = fmaxf(m, b2f(p[n]));
    if (lane < MEM) m = fmaxf(m, memkv[hd * MEM + lane]);
#pragma unroll
    for (int off = 32; off; off >>= 1) m = fmaxf(m, __shfl_xor(m, off));
    float s = 0.f;
    for (int n = lane; n < HW; n += 64) s += __expf(b2f(p[n]) - m);
    if (lane < MEM) s += __expf(memkv[hd * MEM + lane] - m);
#pragma unroll
    for (int off = 32; off; off >>= 1) s += __shfl_xor(s, off);
    if (lane == 0) { rowmax[row] = m; rowsum[row] = s; }
}

// K6: partial context over 512-col chunks
__global__ __launch_bounds__(256) void k_ctx(const short* __restrict__ kv,
                                             const float* __restrict__ memkv,
                                             const float* __restrict__ rowmax,
                                             float* __restrict__ pctx) {
    int chunk = blockIdx.x, bh = blockIdx.y;
    int b = bh >> 2, h = bh & 3;
    int t = threadIdx.x;
    int d = t >> 3;
    int e0 = (t & 7) * 4;
    __shared__ float eks[32][65];
    __shared__ float vs[32][65];
    __shared__ float rmx[32];
    const short* kp = kv + ((size_t)b * 256 + h * DHEAD) * HW;
    const short* vp = kv + ((size_t)b * 256 + 128 + h * DHEAD) * HW;
    if (t < 32) rmx[t] = rowmax[bh * DHEAD + t];
    float acc[4] = {0.f, 0.f, 0.f, 0.f};
    for (int sc = 0; sc < 8; ++sc) {
        int n0 = chunk * 512 + sc * 64;
        __syncthreads();
#pragma unroll
        for (int j = 0; j < 8; ++j) {
            int e = t + j * 256; int rr = e >> 6, cc = e & 63;
            eks[rr][cc] = __expf(b2f(kp[(size_t)rr * HW + n0 + cc]) - rmx[rr]);
            vs[rr][cc]  = b2f(vp[(size_t)rr * HW + n0 + cc]);
        }
        __syncthreads();
#pragma unroll 8
        for (int n = 0; n < 64; ++n) {
            float ek = eks[d][n];
            acc[0] += ek * vs[e0 + 0][n];
            acc[1] += ek * vs[e0 + 1][n];
            acc[2] += ek * vs[e0 + 2][n];
            acc[3] += ek * vs[e0 + 3][n];
        }
    }
    if (chunk == 0) {
#pragma unroll
        for (int m2 = 0; m2 < MEM; ++m2) {
            float ek = __expf(memkv[(h * DHEAD + d) * MEM + m2] - rmx[d]);
            acc[0] += ek * memkv[512 + (h * DHEAD + e0 + 0) * MEM + m2];
            acc[1] += ek * memkv[512 + (h * DHEAD + e0 + 1) * MEM + m2];
            acc[2] += ek * memkv[512 + (h * DHEAD + e0 + 2) * MEM + m2];
            acc[3] += ek * memkv[512 + (h * DHEAD + e0 + 3) * MEM + m2];
        }
    }
    float* o = pctx + ((size_t)chunk * 64 + bh) * 1024;
    o[d * 32 + e0 + 0] = acc[0];
    o[d * 32 + e0 + 1] = acc[1];
    o[d * 32 + e0 + 2] = acc[2];
    o[d * 32 + e0 + 3] = acc[3];
}

// K7: reduce partials, normalize, fold w_out -> Mmat[b][o][hd] (bf16)
__global__ void k_M(const float* __restrict__ pctx, const float* __restrict__ rowsum,
                    const float* __restrict__ wout, short* __restrict__ Mmat) {
    int b = blockIdx.x; int t = threadIdx.x;
    __shared__ float ctx[HEADS][DHEAD][DHEAD];
#pragma unroll
    for (int j = 0; j < 16; ++j) {
        int e = t + j * 256;
        int h = e >> 10, dd = (e >> 5) & 31, ee = e & 31;
        float s = 0.f;
#pragma unroll
        for (int c = 0; c < 8; ++c) s += pctx[((size_t)c * 64 + b * 4 + h) * 1024 + (e & 1023)];
        ctx[h][dd][ee] = s / rowsum[(b * 4 + h) * DHEAD + dd];
    }
    __syncthreads();
    int o = t;
    for (int hd = 0; hd < HIDDEN; ++hd) {
        int h = hd >> 5, dd = hd & 31;
        float s = 0.f;
#pragma unroll
        for (int e = 0; e < DHEAD; ++e) s += wout[o * HIDDEN + h * DHEAD + e] * ctx[h][dd][e];
        Mmat[((size_t)b * DIM + o) * HIDDEN + hd] = f2bs(s);
    }
}

// K8: MFMA GEMM pre = M[b] @ qT^T + bias; also per-column partial sumsq -> psum
__global__ __launch_bounds__(256) void k_out(const short* __restrict__ Mmat,
                                             const short* __restrict__ qT,
                                             const float* __restrict__ bout,
                                             short* __restrict__ pre,
                                             float* __restrict__ psum) {
    int nt = blockIdx.x, mt = blockIdx.y, b = blockIdx.z;
    __shared__ short As[128 * 64];
    __shared__ short Bs[128 * 64];
    __shared__ float ps2[2][2][64];
    int t = threadIdx.x;
    int wave = t >> 6, lane = t & 63;
    int wr = wave >> 1, wc = wave & 1;
    int lr = lane & 15, lg = lane >> 4;
    const short* Ag = Mmat + ((size_t)b * 256 + mt * 128) * 128;
    const short* Bg = qT + (size_t)b * HW * 128 + (size_t)nt * 128 * 128;
    const f32x4 fz = {0.f, 0.f, 0.f, 0.f};
    f32x4 acc[4][4];
#pragma unroll
    for (int m = 0; m < 4; ++m)
#pragma unroll
        for (int n = 0; n < 4; ++n) acc[m][n] = fz;

    for (int kk = 0; kk < 128; kk += 64) {
        if (kk) __syncthreads();
#pragma unroll
        for (int is = 0; is < 4; ++is) {
            int o = is * 4096 + t * 16;
            int rr2 = o >> 7;
            int js = ((o >> 4) & 7) ^ (rr2 & 7);
            gld_lds16(Ag + (size_t)rr2 * 128 + kk + js * 8, (char*)As + o);
            gld_lds16(Bg + (size_t)rr2 * 128 + kk + js * 8, (char*)Bs + o);
        }
        __syncthreads();
#pragma unroll
        for (int ks = 0; ks < 2; ++ks) {
            bf16x8 av[4], bv[4];
            int j = lg + 4 * ks;
#pragma unroll
            for (int m = 0; m < 4; ++m) {
                int row = wr * 64 + m * 16 + lr;
                av[m] = *(const bf16x8*)((const char*)As + row * 128 + ((j ^ (row & 7)) << 4));
            }
#pragma unroll
            for (int n = 0; n < 4; ++n) {
                int row = wc * 64 + n * 16 + lr;
                bv[n] = *(const bf16x8*)((const char*)Bs + row * 128 + ((j ^ (row & 7)) << 4));
            }
#pragma unroll
            for (int m = 0; m < 4; ++m)
#pragma unroll
                for (int n = 0; n < 4; ++n)
                    acc[m][n] = __builtin_amdgcn_mfma_f32_16x16x32_bf16(av[m], bv[n], acc[m][n], 0, 0, 0);
        }
    }
    float bb[4][4];
#pragma unroll
    for (int m = 0; m < 4; ++m)
#pragma unroll
        for (int q = 0; q < 4; ++q)
            bb[m][q] = bout[mt * 128 + wr * 64 + m * 16 + lg * 4 + q];
    int gcol0 = nt * 128 + wc * 64 + lr;
    short* outp = pre + (size_t)b * 256 * HW;
    float ssn[4] = {0.f, 0.f, 0.f, 0.f};
#pragma unroll
    for (int n = 0; n < 4; ++n) {
        int gcol = gcol0 + n * 16;
#pragma unroll
        for (int m = 0; m < 4; ++m)
#pragma unroll
            for (int q = 0; q < 4; ++q) {
                int grow = mt * 128 + wr * 64 + m * 16 + lg * 4 + q;
                float val = acc[m][n][q] + bb[m][q];
                outp[(size_t)grow * HW + gcol] = f2bs(val);
                ssn[n] += val * val;
            }
    }
#pragma unroll
    for (int n = 0; n < 4; ++n) {
        ssn[n] += __shfl_xor(ssn[n], 16);
        ssn[n] += __shfl_xor(ssn[n], 32);
    }
    if (lg == 0) {
#pragma unroll
        for (int n = 0; n < 4; ++n) ps2[wr][wc][n * 16 + lr] = ssn[n];
    }
    __syncthreads();
    if (t < 128) {
        int wc2 = t >> 6, col = t & 63;
        psum[((size_t)mt * NB + b) * HW + nt * 128 + wc2 * 64 + col] =
            ps2[0][wc2][col] + ps2[1][wc2][col];
    }
}

// K9: r2 = 16/max(||pre col||, eps)
__global__ void k_rfin2(const float* __restrict__ psum, float* __restrict__ r2) {
    int i = blockIdx.x * 256 + threadIdx.x;
    r2[i] = 16.0f / fmaxf(sqrtf(psum[i] + psum[65536 + i]), 1e-12f);
}

// K10: out = pre * r2 * g2 (vectorized bf16x8 read, f32 write)
__global__ void k_scale(const short* __restrict__ pre, const float* __restrict__ r2,
                        const float* __restrict__ g2, float* __restrict__ out) {
    int idx = blockIdx.x * 256 + threadIdx.x;       // 2,097,152 threads, 8 elems each
    int n8 = idx & 511, c = (idx >> 9) & 255, b = idx >> 17;
    size_t base = ((size_t)b * 256 + c) * HW + n8 * 8;
    bf16x8 v = *(const bf16x8*)(pre + base);
    float g = g2[c];
    const float* rp = r2 + (size_t)b * HW + n8 * 8;
    float* po = out + base;
#pragma unroll
    for (int j = 0; j < 8; ++j) po[j] = b2f(v[j]) * rp[j] * g;
}

extern "C" void kernel_launch(void* const* d_in, const int* in_sizes, int n_in,
                              void* d_out, int out_size, void* d_ws, size_t ws_size,
                              hipStream_t stream) {
    const float* x     = (const float*)d_in[0];
    const float* g1    = (const float*)d_in[1];
    const float* wqkv  = (const float*)d_in[2];
    const float* memkv = (const float*)d_in[3];
    const float* wout  = (const float*)d_in[4];
    const float* bout  = (const float*)d_in[5];
    const float* g2    = (const float*)d_in[6];
    float* out = (float*)d_out;
    char* ws = (char*)d_ws;

    short* w1b  = (short*)(ws + OFF_W1B);
    float* r    = (float*)(ws + OFF_R);
    float* rpart= (float*)(ws + OFF_RP);
    float* rmax = (float*)(ws + OFF_RMAX);
    float* rsum = (float*)(ws + OFF_RSUM);
    float* pctx = (float*)(ws + OFF_PCTX);
    short* Mmat = (short*)(ws + OFF_M);
    float* psum = (float*)(ws + OFF_PSUM);
    float* r2   = (float*)(ws + OFF_R2);
    short* qT   = (short*)(ws + OFF_QT);
    short* kv   = (short*)(ws + OFF_KV);
    short* xT   = (short*)(ws + OFF_XT);
    short* pre  = xT;   // xT dead after k_qkv; reuse for pre

    k_prep<<<384, 256, 0, stream>>>(wqkv, g1, w1b);
    k_tr<<<dim3(64, 4, NB), 256, 0, stream>>>(x, xT, rpart);
    k_rfin<<<256, 256, 0, stream>>>(rpart, r);
    k_qkv<<<dim3(32, 3, NB), 256, 0, stream>>>(w1b, xT, r, kv, qT);
    k_kstats<<<512, 256, 0, stream>>>(kv, memkv, rmax, rsum);
    k_ctx<<<dim3(8, 64), 256, 0, stream>>>(kv, memkv, rmax, pctx);
    k_M<<<NB, 256, 0, stream>>>(pctx, rsum, wout, Mmat);
    k_out<<<dim3(32, 2, NB), 256, 0, stream>>>(Mmat, qT, bout, pre, psum);
    k_rfin2<<<256, 256, 0, stream>>>(psum, r2);
    k_scale<<<8192, 256, 0, stream>>>(pre, r2, g2, out);
}

// Round 3
// 139.787 us; speedup vs baseline: 3.5584x; 1.6007x over previous
//
#include <hip/hip_runtime.h>
#include <hip/hip_bf16.h>

#define NB 16
#define DIM 256
#define HW 4096
#define HEADS 4
#define DHEAD 32
#define MEM 4
#define HIDDEN 128

typedef __hip_bfloat16 bf16;
typedef __attribute__((ext_vector_type(8))) short bf16x8;   // 8 bf16 = 4 VGPR (guide §3)
typedef __attribute__((ext_vector_type(4))) float f32x4;
typedef __attribute__((ext_vector_type(4))) unsigned short us4;

#define AS1 __attribute__((address_space(1)))
#define AS3 __attribute__((address_space(3)))

__device__ __forceinline__ void gld_lds16(const void* g, void* l) {
    __builtin_amdgcn_global_load_lds((const AS1 void*)g, (AS3 void*)l, 16, 0, 0);
}
__device__ __forceinline__ float b2f(short s) {
    union { unsigned int u; float f; } x; x.u = ((unsigned int)(unsigned short)s) << 16; return x.f;
}
__device__ __forceinline__ short f2bs(float f) {
    bf16 h = __float2bfloat16(f);
    return *reinterpret_cast<short*>(&h);
}

// ---- ws layout (bytes) ----
constexpr size_t OFF_W1B  = 0;                                   // 98304 bf16
constexpr size_t OFF_R    = OFF_W1B + 98304*2;                   // 65536 f32
constexpr size_t OFF_RP   = OFF_R + 65536*4;                     // 4*65536 f32
constexpr size_t OFF_RMAX = OFF_RP + 4*65536*4;                  // 2048 f32
constexpr size_t OFF_RSUM = OFF_RMAX + 2048*4;                   // 2048 f32
constexpr size_t OFF_PCTX = OFF_RSUM + 2048*4;                   // 8*64*1024 f32
constexpr size_t OFF_M    = OFF_PCTX + 8*64*1024*4;              // 16*256*128 bf16
constexpr size_t OFF_PSUM = OFF_M + (size_t)NB*DIM*HIDDEN*2;     // 2*65536 f32
constexpr size_t OFF_R2   = OFF_PSUM + 2*65536*4;                // 65536 f32
constexpr size_t OFF_QT   = OFF_R2 + 65536*4;                    // 16*4096*128 bf16 (~16.8MB)
constexpr size_t OFF_KV   = OFF_QT + (size_t)NB*HW*HIDDEN*2;     // 16*256*4096 bf16 (~33.6MB)
constexpr size_t OFF_XT   = OFF_KV + (size_t)NB*256*HW*2;        // 16*4096*256 bf16 (~33.6MB); reused as `pre`

// K1: w1b = bf16(w_qkv * g1)
__global__ void k_prep(const float* __restrict__ wqkv, const float* __restrict__ g1,
                       short* __restrict__ w1b) {
    int i = blockIdx.x * 256 + threadIdx.x;     // 98304
    w1b[i] = f2bs(wqkv[i] * g1[i & (DIM - 1)]);
}

// K2: transpose x -> xT[b][n][c] (bf16) + partial sumsq per (b,n) over 64-c stripe
__global__ __launch_bounds__(256) void k_tr(const float* __restrict__ x,
                                            short* __restrict__ xT,
                                            float* __restrict__ rpart) {
    int n0 = blockIdx.x * 64, cy = blockIdx.y, b = blockIdx.z;
    int c0 = cy * 64;
    __shared__ short xs[64 * 65];
    __shared__ float ps[4][64];
    int t = threadIdx.x;
    int ln = t & 63, cb = t >> 6;
    const float* xp = x + ((size_t)b * DIM + c0) * HW + n0;
    float ss = 0.f;
#pragma unroll
    for (int j = 0; j < 16; ++j) {
        int c = cb * 16 + j;
        float v = xp[(size_t)c * HW + ln];
        ss += v * v;
        xs[c * 65 + ln] = f2bs(v);
    }
    ps[cb][ln] = ss;
    __syncthreads();
    if (t < 64)
        rpart[((size_t)cy * NB + b) * HW + n0 + t] = ps[0][t] + ps[1][t] + ps[2][t] + ps[3][t];
    int n = t >> 2, ch = t & 3;
    short tmp[16];
#pragma unroll
    for (int i = 0; i < 16; ++i) tmp[i] = xs[(ch * 16 + i) * 65 + n];
    short* o = xT + ((size_t)b * HW + n0 + n) * DIM + c0 + ch * 16;
    *(bf16x8*)(o)     = *(bf16x8*)(tmp);
    *(bf16x8*)(o + 8) = *(bf16x8*)(tmp + 8);
}

// K3: r = 16 / max(||x||, eps)
__global__ void k_rfin(const float* __restrict__ rpart, float* __restrict__ r) {
    int i = blockIdx.x * 256 + threadIdx.x;
    float s = rpart[i] + rpart[65536 + i] + rpart[131072 + i] + rpart[196608 + i];
    r[i] = 16.0f / fmaxf(sqrtf(s), 1e-12f);
}

// K4: MFMA GEMM qkv = (w1b @ xT^T) * r.  mt==0 -> fused q-softmax -> qT[n][hd];
//     mt==1,2 -> k,v rows into kv buffer.
__global__ __launch_bounds__(256) void k_qkv(const short* __restrict__ w1b,
                                             const short* __restrict__ xT,
                                             const float* __restrict__ r,
                                             short* __restrict__ kv,
                                             short* __restrict__ qT) {
    int nt = blockIdx.x, mt = blockIdx.y, b = blockIdx.z;
    __shared__ short As[128 * 64];
    __shared__ short Bs[128 * 64];
    int t = threadIdx.x;
    int wave = t >> 6, lane = t & 63;
    int wr = wave >> 1, wc = wave & 1;
    int lr = lane & 15, lg = lane >> 4;
    const short* Ag = w1b + (size_t)mt * 128 * 256;
    const short* Bg = xT + ((size_t)b * HW + nt * 128) * 256;
    const f32x4 fz = {0.f, 0.f, 0.f, 0.f};
    f32x4 acc[4][4];
#pragma unroll
    for (int m = 0; m < 4; ++m)
#pragma unroll
        for (int n = 0; n < 4; ++n) acc[m][n] = fz;

    for (int kk = 0; kk < 256; kk += 64) {
        if (kk) __syncthreads();
#pragma unroll
        for (int is = 0; is < 4; ++is) {
            int o = is * 4096 + t * 16;          // byte offset, linear LDS dest
            int rr2 = o >> 7;                    // 128 B per row
            int js = ((o >> 4) & 7) ^ (rr2 & 7); // pre-swizzled global source (T2/m173)
            gld_lds16(Ag + (size_t)rr2 * 256 + kk + js * 8, (char*)As + o);
            gld_lds16(Bg + (size_t)rr2 * 256 + kk + js * 8, (char*)Bs + o);
        }
        __syncthreads();
#pragma unroll
        for (int ks = 0; ks < 2; ++ks) {
            bf16x8 av[4], bv[4];
            int j = lg + 4 * ks;
#pragma unroll
            for (int m = 0; m < 4; ++m) {
                int row = wr * 64 + m * 16 + lr;
                av[m] = *(const bf16x8*)((const char*)As + row * 128 + ((j ^ (row & 7)) << 4));
            }
#pragma unroll
            for (int n = 0; n < 4; ++n) {
                int row = wc * 64 + n * 16 + lr;
                bv[n] = *(const bf16x8*)((const char*)Bs + row * 128 + ((j ^ (row & 7)) << 4));
            }
#pragma unroll
            for (int m = 0; m < 4; ++m)
#pragma unroll
                for (int n = 0; n < 4; ++n)
                    acc[m][n] = __builtin_amdgcn_mfma_f32_16x16x32_bf16(av[m], bv[n], acc[m][n], 0, 0, 0);
        }
    }
    int gcol0 = nt * 128 + wc * 64 + lr;
    float rv[4];
#pragma unroll
    for (int n = 0; n < 4; ++n) rv[n] = r[(size_t)b * HW + gcol0 + n * 16];

    if (mt == 0) {
#pragma unroll
        for (int n = 0; n < 4; ++n) {
            int gcol = gcol0 + n * 16;
#pragma unroll
            for (int a = 0; a < 2; ++a) {
                float v[8];
#pragma unroll
                for (int mm = 0; mm < 2; ++mm)
#pragma unroll
                    for (int q = 0; q < 4; ++q)
                        v[mm * 4 + q] = acc[2 * a + mm][n][q] * rv[n];
                float mx = v[0];
#pragma unroll
                for (int i = 1; i < 8; ++i) mx = fmaxf(mx, v[i]);
                mx = fmaxf(mx, __shfl_xor(mx, 16));
                mx = fmaxf(mx, __shfl_xor(mx, 32));
                float sum = 0.f;
#pragma unroll
                for (int i = 0; i < 8; ++i) { v[i] = __expf(v[i] - mx); sum += v[i]; }
                sum += __shfl_xor(sum, 16);
                sum += __shfl_xor(sum, 32);
                float inv = 0.17677669529663689f / sum;   // dhead^-0.5 / sum
                size_t base = ((size_t)b * HW + gcol) * 128 + (wr * 2 + a) * 32 + lg * 4;
#pragma unroll
                for (int mm = 0; mm < 2; ++mm) {
                    us4 pk;
#pragma unroll
                    for (int q = 0; q < 4; ++q)
                        pk[q] = (unsigned short)f2bs(v[mm * 4 + q] * inv);
                    *(us4*)(qT + base + mm * 16) = pk;
                }
            }
        }
    } else {
        short* outp = kv + ((size_t)b * 256 + (mt - 1) * 128) * HW;
#pragma unroll
        for (int n = 0; n < 4; ++n) {
            int gcol = gcol0 + n * 16;
#pragma unroll
            for (int m = 0; m < 4; ++m)
#pragma unroll
                for (int q = 0; q < 4; ++q) {
                    int grow = wr * 64 + m * 16 + lg * 4 + q;
                    outp[(size_t)grow * HW + gcol] = f2bs(acc[m][n][q] * rv[n]);
                }
        }
    }
}

// K5: k-row max & sum(exp): single-pass online, bf16x8 loads
__global__ void k_kstats(const short* __restrict__ kv, const float* __restrict__ memkv,
                         float* __restrict__ rowmax, float* __restrict__ rowsum) {
    int row = blockIdx.x * 4 + (threadIdx.x >> 6);  // b*128 + hd
    int lane = threadIdx.x & 63;
    int b = row >> 7, hd = row & 127;
    const short* p = kv + ((size_t)b * 256 + hd) * HW;
    float m = -1e30f, s = 0.f;
    for (int n0 = lane * 8; n0 < HW; n0 += 512) {
        bf16x8 v8 = *(const bf16x8*)(p + n0);
        float v[8]; float lm = -1e30f;
#pragma unroll
        for (int j = 0; j < 8; ++j) { v[j] = b2f(v8[j]); lm = fmaxf(lm, v[j]); }
        float mn = fmaxf(m, lm);
        float add = 0.f;
#pragma unroll
        for (int j = 0; j < 8; ++j) add += __expf(v[j] - mn);
        s = s * __expf(m - mn) + add;
        m = mn;
    }
    if (lane < MEM) {
        float v = memkv[hd * MEM + lane];
        float mn = fmaxf(m, v);
        s = s * __expf(m - mn) + __expf(v - mn);
        m = mn;
    }
#pragma unroll
    for (int off = 32; off; off >>= 1) {
        float mo = __shfl_xor(m, off), so = __shfl_xor(s, off);
        float mn = fmaxf(m, mo);
        s = s * __expf(m - mn) + so * __expf(mo - mn);
        m = mn;
    }
    if (lane == 0) { rowmax[row] = m; rowsum[row] = s; }
}

// K6: partial context over 512-col chunks (bf16x8 staged loads)
__global__ __launch_bounds__(256) void k_ctx(const short* __restrict__ kv,
                                             const float* __restrict__ memkv,
                                             const float* __restrict__ rowmax,
                                             float* __restrict__ pctx) {
    int chunk = blockIdx.x, bh = blockIdx.y;
    int b = bh >> 2, h = bh & 3;
    int t = threadIdx.x;
    int d = t >> 3;
    int e0 = (t & 7) * 4;
    int srr = t >> 3, scc = (t & 7) * 8;     // staging map: 32 rows x 64 cols, 8/thread
    __shared__ float eks[32][65];
    __shared__ float vs[32][65];
    __shared__ float rmx[32];
    const short* kp = kv + ((size_t)b * 256 + h * DHEAD) * HW;
    const short* vp = kv + ((size_t)b * 256 + 128 + h * DHEAD) * HW;
    if (t < 32) rmx[t] = rowmax[bh * DHEAD + t];
    float acc[4] = {0.f, 0.f, 0.f, 0.f};
    for (int sc = 0; sc < 8; ++sc) {
        int n0 = chunk * 512 + sc * 64;
        __syncthreads();
        bf16x8 k8 = *(const bf16x8*)(kp + (size_t)srr * HW + n0 + scc);
        bf16x8 v8 = *(const bf16x8*)(vp + (size_t)srr * HW + n0 + scc);
        float rm = rmx[srr];
#pragma unroll
        for (int j = 0; j < 8; ++j) {
            eks[srr][scc + j] = __expf(b2f(k8[j]) - rm);
            vs[srr][scc + j]  = b2f(v8[j]);
        }
        __syncthreads();
#pragma unroll 8
        for (int n = 0; n < 64; ++n) {
            float ek = eks[d][n];
            acc[0] += ek * vs[e0 + 0][n];
            acc[1] += ek * vs[e0 + 1][n];
            acc[2] += ek * vs[e0 + 2][n];
            acc[3] += ek * vs[e0 + 3][n];
        }
    }
    if (chunk == 0) {
#pragma unroll
        for (int m2 = 0; m2 < MEM; ++m2) {
            float ek = __expf(memkv[(h * DHEAD + d) * MEM + m2] - rmx[d]);
            acc[0] += ek * memkv[512 + (h * DHEAD + e0 + 0) * MEM + m2];
            acc[1] += ek * memkv[512 + (h * DHEAD + e0 + 1) * MEM + m2];
            acc[2] += ek * memkv[512 + (h * DHEAD + e0 + 2) * MEM + m2];
            acc[3] += ek * memkv[512 + (h * DHEAD + e0 + 3) * MEM + m2];
        }
    }
    float* o = pctx + ((size_t)chunk * 64 + bh) * 1024;
    o[d * 32 + e0 + 0] = acc[0];
    o[d * 32 + e0 + 1] = acc[1];
    o[d * 32 + e0 + 2] = acc[2];
    o[d * 32 + e0 + 3] = acc[3];
}

// K7: reduce partials, normalize, fold w_out -> Mmat[b][o][hd].
// Parallel version: grid (8 o-groups, NB). Anti-conflict padded LDS.
__global__ __launch_bounds__(256) void k_M(const float* __restrict__ pctx,
                                           const float* __restrict__ rowsum,
                                           const float* __restrict__ wout,
                                           short* __restrict__ Mmat) {
    int og = blockIdx.x, b = blockIdx.y;
    __shared__ float ctx[4 * 33 * 33];      // [h][dd][ee], idx = h*1089 + dd*33 + ee
    __shared__ float wsw[32 * 136];         // [row][h*34 + e]
    int t = threadIdx.x;
#pragma unroll
    for (int j = 0; j < 16; ++j) {
        int e = t + j * 256;                // h*1024 + dd*32 + ee
        int h = e >> 10, dd = (e >> 5) & 31, ee = e & 31;
        float s = 0.f;
#pragma unroll
        for (int c = 0; c < 8; ++c) s += pctx[((size_t)c * 64 + b * 4 + h) * 1024 + (e & 1023)];
        ctx[h * 1089 + dd * 33 + ee] = s / rowsum[(b * 4 + h) * DHEAD + dd];
    }
#pragma unroll
    for (int j = 0; j < 4; ++j) {
        int e4 = t + j * 256;               // 1024 float4 = 32 rows x 128
        int row = e4 >> 5, c = (e4 & 31) * 4;
        f32x4 w4 = *(const f32x4*)(wout + (size_t)(og * 32 + row) * HIDDEN + c);
        *(f32x4*)(wsw + row * 136 + (c >> 5) * 34 + (c & 31)) = w4;
    }
    __syncthreads();
    int ol = t >> 3, hg = t & 7;
    short out16[16];
#pragma unroll
    for (int ii = 0; ii < 16; ++ii) {
        int hd = hg * 16 + ii;
        int h = hd >> 5, dd = hd & 31;
        float s = 0.f;
#pragma unroll
        for (int e = 0; e < 32; ++e)
            s += wsw[ol * 136 + h * 34 + e] * ctx[h * 1089 + dd * 33 + e];
        out16[ii] = f2bs(s);
    }
    short* op = Mmat + ((size_t)(b * 256 + og * 32 + ol)) * 128 + hg * 16;
    *(bf16x8*)(op)     = *(bf16x8*)(out16);
    *(bf16x8*)(op + 8) = *(bf16x8*)(out16 + 8);
}

// K8: MFMA GEMM pre = M[b] @ qT^T + bias; also per-column partial sumsq -> psum
__global__ __launch_bounds__(256) void k_out(const short* __restrict__ Mmat,
                                             const short* __restrict__ qT,
                                             const float* __restrict__ bout,
                                             short* __restrict__ pre,
                                             float* __restrict__ psum) {
    int nt = blockIdx.x, mt = blockIdx.y, b = blockIdx.z;
    __shared__ short As[128 * 64];
    __shared__ short Bs[128 * 64];
    __shared__ float ps2[2][2][64];
    int t = threadIdx.x;
    int wave = t >> 6, lane = t & 63;
    int wr = wave >> 1, wc = wave & 1;
    int lr = lane & 15, lg = lane >> 4;
    const short* Ag = Mmat + ((size_t)b * 256 + mt * 128) * 128;
    const short* Bg = qT + (size_t)b * HW * 128 + (size_t)nt * 128 * 128;
    const f32x4 fz = {0.f, 0.f, 0.f, 0.f};
    f32x4 acc[4][4];
#pragma unroll
    for (int m = 0; m < 4; ++m)
#pragma unroll
        for (int n = 0; n < 4; ++n) acc[m][n] = fz;

    for (int kk = 0; kk < 128; kk += 64) {
        if (kk) __syncthreads();
#pragma unroll
        for (int is = 0; is < 4; ++is) {
            int o = is * 4096 + t * 16;
            int rr2 = o >> 7;
            int js = ((o >> 4) & 7) ^ (rr2 & 7);
            gld_lds16(Ag + (size_t)rr2 * 128 + kk + js * 8, (char*)As + o);
            gld_lds16(Bg + (size_t)rr2 * 128 + kk + js * 8, (char*)Bs + o);
        }
        __syncthreads();
#pragma unroll
        for (int ks = 0; ks < 2; ++ks) {
            bf16x8 av[4], bv[4];
            int j = lg + 4 * ks;
#pragma unroll
            for (int m = 0; m < 4; ++m) {
                int row = wr * 64 + m * 16 + lr;
                av[m] = *(const bf16x8*)((const char*)As + row * 128 + ((j ^ (row & 7)) << 4));
            }
#pragma unroll
            for (int n = 0; n < 4; ++n) {
                int row = wc * 64 + n * 16 + lr;
                bv[n] = *(const bf16x8*)((const char*)Bs + row * 128 + ((j ^ (row & 7)) << 4));
            }
#pragma unroll
            for (int m = 0; m < 4; ++m)
#pragma unroll
                for (int n = 0; n < 4; ++n)
                    acc[m][n] = __builtin_amdgcn_mfma_f32_16x16x32_bf16(av[m], bv[n], acc[m][n], 0, 0, 0);
        }
    }
    float bb[4][4];
#pragma unroll
    for (int m = 0; m < 4; ++m)
#pragma unroll
        for (int q = 0; q < 4; ++q)
            bb[m][q] = bout[mt * 128 + wr * 64 + m * 16 + lg * 4 + q];
    int gcol0 = nt * 128 + wc * 64 + lr;
    short* outp = pre + (size_t)b * 256 * HW;
    float ssn[4] = {0.f, 0.f, 0.f, 0.f};
#pragma unroll
    for (int n = 0; n < 4; ++n) {
        int gcol = gcol0 + n * 16;
#pragma unroll
        for (int m = 0; m < 4; ++m)
#pragma unroll
            for (int q = 0; q < 4; ++q) {
                int grow = mt * 128 + wr * 64 + m * 16 + lg * 4 + q;
                float val = acc[m][n][q] + bb[m][q];
                outp[(size_t)grow * HW + gcol] = f2bs(val);
                ssn[n] += val * val;
            }
    }
#pragma unroll
    for (int n = 0; n < 4; ++n) {
        ssn[n] += __shfl_xor(ssn[n], 16);
        ssn[n] += __shfl_xor(ssn[n], 32);
    }
    if (lg == 0) {
#pragma unroll
        for (int n = 0; n < 4; ++n) ps2[wr][wc][n * 16 + lr] = ssn[n];
    }
    __syncthreads();
    if (t < 128) {
        int wc2 = t >> 6, col = t & 63;
        psum[((size_t)mt * NB + b) * HW + nt * 128 + wc2 * 64 + col] =
            ps2[0][wc2][col] + ps2[1][wc2][col];
    }
}

// K9: r2 = 16/max(||pre col||, eps)
__global__ void k_rfin2(const float* __restrict__ psum, float* __restrict__ r2) {
    int i = blockIdx.x * 256 + threadIdx.x;
    r2[i] = 16.0f / fmaxf(sqrtf(psum[i] + psum[65536 + i]), 1e-12f);
}

// K10: out = pre * r2 * g2 (vectorized bf16x8 read, f32 write)
__global__ void k_scale(const short* __restrict__ pre, const float* __restrict__ r2,
                        const float* __restrict__ g2, float* __restrict__ out) {
    int idx = blockIdx.x * 256 + threadIdx.x;       // 2,097,152 threads, 8 elems each
    int n8 = idx & 511, c = (idx >> 9) & 255, b = idx >> 17;
    size_t base = ((size_t)b * 256 + c) * HW + n8 * 8;
    bf16x8 v = *(const bf16x8*)(pre + base);
    float g = g2[c];
    const float* rp = r2 + (size_t)b * HW + n8 * 8;
    float* po = out + base;
#pragma unroll
    for (int j = 0; j < 8; ++j) po[j] = b2f(v[j]) * rp[j] * g;
}

extern "C" void kernel_launch(void* const* d_in, const int* in_sizes, int n_in,
                              void* d_out, int out_size, void* d_ws, size_t ws_size,
                              hipStream_t stream) {
    const float* x     = (const float*)d_in[0];
    const float* g1    = (const float*)d_in[1];
    const float* wqkv  = (const float*)d_in[2];
    const float* memkv = (const float*)d_in[3];
    const float* wout  = (const float*)d_in[4];
    const float* bout  = (const float*)d_in[5];
    const float* g2    = (const float*)d_in[6];
    float* out = (float*)d_out;
    char* ws = (char*)d_ws;

    short* w1b  = (short*)(ws + OFF_W1B);
    float* r    = (float*)(ws + OFF_R);
    float* rpart= (float*)(ws + OFF_RP);
    float* rmax = (float*)(ws + OFF_RMAX);
    float* rsum = (float*)(ws + OFF_RSUM);
    float* pctx = (float*)(ws + OFF_PCTX);
    short* Mmat = (short*)(ws + OFF_M);
    float* psum = (float*)(ws + OFF_PSUM);
    float* r2   = (float*)(ws + OFF_R2);
    short* qT   = (short*)(ws + OFF_QT);
    short* kv   = (short*)(ws + OFF_KV);
    short* xT   = (short*)(ws + OFF_XT);
    short* pre  = xT;   // xT dead after k_qkv; reuse for pre

    k_prep<<<384, 256, 0, stream>>>(wqkv, g1, w1b);
    k_tr<<<dim3(64, 4, NB), 256, 0, stream>>>(x, xT, rpart);
    k_rfin<<<256, 256, 0, stream>>>(rpart, r);
    k_qkv<<<dim3(32, 3, NB), 256, 0, stream>>>(w1b, xT, r, kv, qT);
    k_kstats<<<512, 256, 0, stream>>>(kv, memkv, rmax, rsum);
    k_ctx<<<dim3(8, 64), 256, 0, stream>>>(kv, memkv, rmax, pctx);
    k_M<<<dim3(8, NB), 256, 0, stream>>>(pctx, rsum, wout, Mmat);
    k_out<<<dim3(32, 2, NB), 256, 0, stream>>>(Mmat, qT, bout, pre, psum);
    k_rfin2<<<256, 256, 0, stream>>>(psum, r2);
    k_scale<<<8192, 256, 0, stream>>>(pre, r2, g2, out);
}

// Round 4
// 119.216 us; speedup vs baseline: 4.1724x; 1.1726x over previous
//
#include <hip/hip_runtime.h>
#include <hip/hip_bf16.h>

#define NB 16
#define DIM 256
#define HW 4096
#define HEADS 4
#define DHEAD 32
#define MEM 4
#define HIDDEN 128

typedef __hip_bfloat16 bf16;
typedef __attribute__((ext_vector_type(8))) short bf16x8;
typedef __attribute__((ext_vector_type(4))) float f32x4;
typedef __attribute__((ext_vector_type(4))) unsigned short us4;

#define AS1 __attribute__((address_space(1)))
#define AS3 __attribute__((address_space(3)))

__device__ __forceinline__ void gld_lds16(const void* g, void* l) {
    __builtin_amdgcn_global_load_lds((const AS1 void*)g, (AS3 void*)l, 16, 0, 0);
}
__device__ __forceinline__ float b2f(short s) {
    union { unsigned int u; float f; } x; x.u = ((unsigned int)(unsigned short)s) << 16; return x.f;
}
__device__ __forceinline__ short f2bs(float f) {
    bf16 h = __float2bfloat16(f);
    return *reinterpret_cast<short*>(&h);
}

// ---- ws layout (bytes) ----
constexpr size_t OFF_W1B  = 0;                                   // 98304 bf16
constexpr size_t OFF_R    = OFF_W1B + 98304*2;                   // 65536 f32
constexpr size_t OFF_RP   = OFF_R + 65536*4;                     // 4*65536 f32
constexpr size_t OFF_PCTX = OFF_RP + 4*65536*4;                  // 8*64*1056 f32
constexpr size_t OFF_M    = OFF_PCTX + (size_t)8*64*1056*4;      // 16*256*128 bf16
constexpr size_t OFF_QT   = OFF_M + (size_t)NB*DIM*HIDDEN*2;     // 16*4096*128 bf16
constexpr size_t OFF_KV   = OFF_QT + (size_t)NB*HW*HIDDEN*2;     // 16*256*4096 bf16
constexpr size_t OFF_XT   = OFF_KV + (size_t)NB*256*HW*2;        // 16*4096*256 bf16

// K1: w1b = bf16(w_qkv * g1)
__global__ void k_prep(const float* __restrict__ wqkv, const float* __restrict__ g1,
                       short* __restrict__ w1b) {
    int i = blockIdx.x * 256 + threadIdx.x;
    w1b[i] = f2bs(wqkv[i] * g1[i & (DIM - 1)]);
}

// K2: transpose x -> xT[b][n][c] (bf16) + partial sumsq per (b,n)
__global__ __launch_bounds__(256) void k_tr(const float* __restrict__ x,
                                            short* __restrict__ xT,
                                            float* __restrict__ rpart) {
    int n0 = blockIdx.x * 64, cy = blockIdx.y, b = blockIdx.z;
    int c0 = cy * 64;
    __shared__ short xs[64 * 65];
    __shared__ float ps[4][64];
    int t = threadIdx.x;
    int ln = t & 63, cb = t >> 6;
    const float* xp = x + ((size_t)b * DIM + c0) * HW + n0;
    float ss = 0.f;
#pragma unroll
    for (int j = 0; j < 16; ++j) {
        int c = cb * 16 + j;
        float v = xp[(size_t)c * HW + ln];
        ss += v * v;
        xs[c * 65 + ln] = f2bs(v);
    }
    ps[cb][ln] = ss;
    __syncthreads();
    if (t < 64)
        rpart[((size_t)cy * NB + b) * HW + n0 + t] = ps[0][t] + ps[1][t] + ps[2][t] + ps[3][t];
    int n = t >> 2, ch = t & 3;
    short tmp[16];
#pragma unroll
    for (int i = 0; i < 16; ++i) tmp[i] = xs[(ch * 16 + i) * 65 + n];
    short* o = xT + ((size_t)b * HW + n0 + n) * DIM + c0 + ch * 16;
    *(bf16x8*)(o)     = *(bf16x8*)(tmp);
    *(bf16x8*)(o + 8) = *(bf16x8*)(tmp + 8);
}

// K3: r = 16 / max(||x||, eps)
__global__ void k_rfin(const float* __restrict__ rpart, float* __restrict__ r) {
    int i = blockIdx.x * 256 + threadIdx.x;
    float s = rpart[i] + rpart[65536 + i] + rpart[131072 + i] + rpart[196608 + i];
    r[i] = 16.0f / fmaxf(sqrtf(s), 1e-12f);
}

// K4: MFMA GEMM qkv = (w1b @ xT^T) * r. mt==0 -> fused q-softmax -> qT; mt==1,2 -> k,v.
__global__ __launch_bounds__(256) void k_qkv(const short* __restrict__ w1b,
                                             const short* __restrict__ xT,
                                             const float* __restrict__ r,
                                             short* __restrict__ kv,
                                             short* __restrict__ qT) {
    int nt = blockIdx.x, mt = blockIdx.y, b = blockIdx.z;
    __shared__ short As[128 * 64];
    __shared__ short Bs[128 * 64];
    int t = threadIdx.x;
    int wave = t >> 6, lane = t & 63;
    int wr = wave >> 1, wc = wave & 1;
    int lr = lane & 15, lg = lane >> 4;
    const short* Ag = w1b + (size_t)mt * 128 * 256;
    const short* Bg = xT + ((size_t)b * HW + nt * 128) * 256;
    const f32x4 fz = {0.f, 0.f, 0.f, 0.f};
    f32x4 acc[4][4];
#pragma unroll
    for (int m = 0; m < 4; ++m)
#pragma unroll
        for (int n = 0; n < 4; ++n) acc[m][n] = fz;

    for (int kk = 0; kk < 256; kk += 64) {
        if (kk) __syncthreads();
#pragma unroll
        for (int is = 0; is < 4; ++is) {
            int o = is * 4096 + t * 16;
            int rr2 = o >> 7;
            int js = ((o >> 4) & 7) ^ (rr2 & 7);
            gld_lds16(Ag + (size_t)rr2 * 256 + kk + js * 8, (char*)As + o);
            gld_lds16(Bg + (size_t)rr2 * 256 + kk + js * 8, (char*)Bs + o);
        }
        __syncthreads();
#pragma unroll
        for (int ks = 0; ks < 2; ++ks) {
            bf16x8 av[4], bv[4];
            int j = lg + 4 * ks;
#pragma unroll
            for (int m = 0; m < 4; ++m) {
                int row = wr * 64 + m * 16 + lr;
                av[m] = *(const bf16x8*)((const char*)As + row * 128 + ((j ^ (row & 7)) << 4));
            }
#pragma unroll
            for (int n = 0; n < 4; ++n) {
                int row = wc * 64 + n * 16 + lr;
                bv[n] = *(const bf16x8*)((const char*)Bs + row * 128 + ((j ^ (row & 7)) << 4));
            }
#pragma unroll
            for (int m = 0; m < 4; ++m)
#pragma unroll
                for (int n = 0; n < 4; ++n)
                    acc[m][n] = __builtin_amdgcn_mfma_f32_16x16x32_bf16(av[m], bv[n], acc[m][n], 0, 0, 0);
        }
    }
    int gcol0 = nt * 128 + wc * 64 + lr;
    float rv[4];
#pragma unroll
    for (int n = 0; n < 4; ++n) rv[n] = r[(size_t)b * HW + gcol0 + n * 16];

    if (mt == 0) {
#pragma unroll
        for (int n = 0; n < 4; ++n) {
            int gcol = gcol0 + n * 16;
#pragma unroll
            for (int a = 0; a < 2; ++a) {
                float v[8];
#pragma unroll
                for (int mm = 0; mm < 2; ++mm)
#pragma unroll
                    for (int q = 0; q < 4; ++q)
                        v[mm * 4 + q] = acc[2 * a + mm][n][q] * rv[n];
                float mx = v[0];
#pragma unroll
                for (int i = 1; i < 8; ++i) mx = fmaxf(mx, v[i]);
                mx = fmaxf(mx, __shfl_xor(mx, 16));
                mx = fmaxf(mx, __shfl_xor(mx, 32));
                float sum = 0.f;
#pragma unroll
                for (int i = 0; i < 8; ++i) { v[i] = __expf(v[i] - mx); sum += v[i]; }
                sum += __shfl_xor(sum, 16);
                sum += __shfl_xor(sum, 32);
                float inv = 0.17677669529663689f / sum;
                size_t base = ((size_t)b * HW + gcol) * 128 + (wr * 2 + a) * 32 + lg * 4;
#pragma unroll
                for (int mm = 0; mm < 2; ++mm) {
                    us4 pk;
#pragma unroll
                    for (int q = 0; q < 4; ++q)
                        pk[q] = (unsigned short)f2bs(v[mm * 4 + q] * inv);
                    *(us4*)(qT + base + mm * 16) = pk;
                }
            }
        }
    } else {
        short* outp = kv + ((size_t)b * 256 + (mt - 1) * 128) * HW;
#pragma unroll
        for (int n = 0; n < 4; ++n) {
            int gcol = gcol0 + n * 16;
#pragma unroll
            for (int m = 0; m < 4; ++m)
#pragma unroll
                for (int q = 0; q < 4; ++q) {
                    int grow = wr * 64 + m * 16 + lg * 4 + q;
                    outp[(size_t)grow * HW + gcol] = f2bs(acc[m][n][q] * rv[n]);
                }
        }
    }
}

// K5: partial context over 512-col chunks; exp(k) WITHOUT max-subtraction
// (|k| <= ~2 so f32-exact); ones-row gives rowsum partials in pctx[1024+d].
__global__ __launch_bounds__(256) void k_ctx(const short* __restrict__ kv,
                                             float* __restrict__ pctx) {
    int chunk = blockIdx.x, bh = blockIdx.y;
    int b = bh >> 2, h = bh & 3;
    int t = threadIdx.x;
    int d = t >> 3;
    int e0 = (t & 7) * 4;
    int srr = t >> 3, scc = (t & 7) * 8;
    __shared__ float eks[32][65];
    __shared__ float vs[32][65];
    const short* kp = kv + ((size_t)b * 256 + h * DHEAD) * HW;
    const short* vp = kv + ((size_t)b * 256 + 128 + h * DHEAD) * HW;
    float acc[4] = {0.f, 0.f, 0.f, 0.f};
    float rs = 0.f;
    for (int sc = 0; sc < 8; ++sc) {
        int n0 = chunk * 512 + sc * 64;
        __syncthreads();
        bf16x8 k8 = *(const bf16x8*)(kp + (size_t)srr * HW + n0 + scc);
        bf16x8 v8 = *(const bf16x8*)(vp + (size_t)srr * HW + n0 + scc);
#pragma unroll
        for (int j = 0; j < 8; ++j) {
            eks[srr][scc + j] = __expf(b2f(k8[j]));
            vs[srr][scc + j]  = b2f(v8[j]);
        }
        __syncthreads();
#pragma unroll 8
        for (int n = 0; n < 64; ++n) {
            float ek = eks[d][n];
            rs += ek;
            acc[0] += ek * vs[e0 + 0][n];
            acc[1] += ek * vs[e0 + 1][n];
            acc[2] += ek * vs[e0 + 2][n];
            acc[3] += ek * vs[e0 + 3][n];
        }
    }
    float* o = pctx + ((size_t)chunk * 64 + bh) * 1056;
    o[d * 32 + e0 + 0] = acc[0];
    o[d * 32 + e0 + 1] = acc[1];
    o[d * 32 + e0 + 2] = acc[2];
    o[d * 32 + e0 + 3] = acc[3];
    if ((t & 7) == 0) o[1024 + d] = rs;
}

// K6: reduce partials + mem-KV terms, normalize, fold w_out -> Mmat[b][o][hd]
__global__ __launch_bounds__(256) void k_M(const float* __restrict__ pctx,
                                           const float* __restrict__ memkv,
                                           const float* __restrict__ wout,
                                           short* __restrict__ Mmat) {
    int og = blockIdx.x, b = blockIdx.y;
    __shared__ float ctx[4 * 33 * 33];
    __shared__ float wsw[32 * 136];
    __shared__ float rsum_s[128];
    int t = threadIdx.x;
    if (t < 128) {      // rowsum: spatial partials + mem exp terms
        int dd = t & 31;
        float s = 0.f;
#pragma unroll
        for (int c = 0; c < 8; ++c)
            s += pctx[((size_t)c * 64 + b * 4 + (t >> 5)) * 1056 + 1024 + dd];
#pragma unroll
        for (int m2 = 0; m2 < MEM; ++m2) s += __expf(memkv[t * MEM + m2]);
        rsum_s[t] = s;
    }
#pragma unroll
    for (int j = 0; j < 4; ++j) {
        int e4 = t + j * 256;
        int row = e4 >> 5, c = (e4 & 31) * 4;
        f32x4 w4 = *(const f32x4*)(wout + (size_t)(og * 32 + row) * HIDDEN + c);
        *(f32x4*)(wsw + row * 136 + (c >> 5) * 34 + (c & 31)) = w4;
    }
    __syncthreads();
#pragma unroll
    for (int j = 0; j < 16; ++j) {
        int e = t + j * 256;
        int h = e >> 10, dd = (e >> 5) & 31, ee = e & 31;
        float s = 0.f;
#pragma unroll
        for (int c = 0; c < 8; ++c) s += pctx[((size_t)c * 64 + b * 4 + h) * 1056 + (e & 1023)];
#pragma unroll
        for (int m2 = 0; m2 < MEM; ++m2)
            s += __expf(memkv[(h * DHEAD + dd) * MEM + m2]) * memkv[512 + (h * DHEAD + ee) * MEM + m2];
        ctx[h * 1089 + dd * 33 + ee] = s / rsum_s[h * 32 + dd];
    }
    __syncthreads();
    int ol = t >> 3, hg = t & 7;
    short out16[16];
#pragma unroll
    for (int ii = 0; ii < 16; ++ii) {
        int hd = hg * 16 + ii;
        int h = hd >> 5, dd = hd & 31;
        float s = 0.f;
#pragma unroll
        for (int e = 0; e < 32; ++e)
            s += wsw[ol * 136 + h * 34 + e] * ctx[h * 1089 + dd * 33 + e];
        out16[ii] = f2bs(s);
    }
    short* op = Mmat + ((size_t)(b * 256 + og * 32 + ol)) * 128 + hg * 16;
    *(bf16x8*)(op)     = *(bf16x8*)(out16);
    *(bf16x8*)(op + 8) = *(bf16x8*)(out16 + 8);
}

// K7: fused final GEMM + bias + column RMS-norm + g2 scale -> f32 out.
// Block computes ALL 256 rows x 64 cols; 4 waves stacked vertically.
__global__ __launch_bounds__(256) void k_out2(const short* __restrict__ Mmat,
                                              const short* __restrict__ qT,
                                              const float* __restrict__ bout,
                                              const float* __restrict__ g2,
                                              float* __restrict__ out) {
    int nt = blockIdx.x, b = blockIdx.y;
    __shared__ short As[256 * 64];      // 256 rows x 64 k (one K-half), 32KB
    __shared__ short Bs[64 * 64];       // 64 n x 64 k, 8KB
    __shared__ float sw[4][80];
    __shared__ float r2s[64];
    int t = threadIdx.x;
    int wave = t >> 6, lane = t & 63;
    int lr = lane & 15, lg = lane >> 4;
    const short* Ag = Mmat + (size_t)b * 256 * 128;
    const short* Bg = qT + ((size_t)b * HW + nt * 64) * 128;
    const f32x4 fz = {0.f, 0.f, 0.f, 0.f};
    f32x4 acc[4][4];
#pragma unroll
    for (int m = 0; m < 4; ++m)
#pragma unroll
        for (int n = 0; n < 4; ++n) acc[m][n] = fz;

    for (int kk = 0; kk < 128; kk += 64) {
        if (kk) __syncthreads();
#pragma unroll
        for (int is = 0; is < 8; ++is) {        // A: 32KB
            int o = is * 4096 + t * 16;
            int rr2 = o >> 7;
            int js = ((o >> 4) & 7) ^ (rr2 & 7);
            gld_lds16(Ag + (size_t)rr2 * 128 + kk + js * 8, (char*)As + o);
        }
#pragma unroll
        for (int is = 0; is < 2; ++is) {        // B: 8KB
            int o = is * 4096 + t * 16;
            int rr2 = o >> 7;
            int js = ((o >> 4) & 7) ^ (rr2 & 7);
            gld_lds16(Bg + (size_t)rr2 * 128 + kk + js * 8, (char*)Bs + o);
        }
        __syncthreads();
#pragma unroll
        for (int ks = 0; ks < 2; ++ks) {
            bf16x8 av[4], bv[4];
            int j = lg + 4 * ks;
#pragma unroll
            for (int m = 0; m < 4; ++m) {
                int row = wave * 64 + m * 16 + lr;
                av[m] = *(const bf16x8*)((const char*)As + row * 128 + ((j ^ (row & 7)) << 4));
            }
#pragma unroll
            for (int n = 0; n < 4; ++n) {
                int row = n * 16 + lr;
                bv[n] = *(const bf16x8*)((const char*)Bs + row * 128 + ((j ^ (row & 7)) << 4));
            }
#pragma unroll
            for (int m = 0; m < 4; ++m)
#pragma unroll
                for (int n = 0; n < 4; ++n)
                    acc[m][n] = __builtin_amdgcn_mfma_f32_16x16x32_bf16(av[m], bv[n], acc[m][n], 0, 0, 0);
        }
    }
    // bias + column sumsq
    float bb[4][4], gg[4][4];
#pragma unroll
    for (int m = 0; m < 4; ++m)
#pragma unroll
        for (int q = 0; q < 4; ++q) {
            int row = wave * 64 + m * 16 + lg * 4 + q;
            bb[m][q] = bout[row];
            gg[m][q] = g2[row];
        }
    float ssn[4] = {0.f, 0.f, 0.f, 0.f};
#pragma unroll
    for (int n = 0; n < 4; ++n)
#pragma unroll
        for (int m = 0; m < 4; ++m)
#pragma unroll
            for (int q = 0; q < 4; ++q) {
                float val = acc[m][n][q] + bb[m][q];
                acc[m][n][q] = val;
                ssn[n] += val * val;
            }
#pragma unroll
    for (int n = 0; n < 4; ++n) {
        ssn[n] += __shfl_xor(ssn[n], 16);
        ssn[n] += __shfl_xor(ssn[n], 32);
    }
    if (lg == 0) {
#pragma unroll
        for (int n = 0; n < 4; ++n) sw[wave][n * 16 + lr] = ssn[n];
    }
    __syncthreads();
    if (t < 64) {
        float s = sw[0][t] + sw[1][t] + sw[2][t] + sw[3][t];
        r2s[t] = 16.0f / fmaxf(sqrtf(s), 1e-12f);
    }
    __syncthreads();
    float* op = out + (size_t)b * DIM * HW + nt * 64;
#pragma unroll
    for (int n = 0; n < 4; ++n) {
        float rc = r2s[n * 16 + lr];
#pragma unroll
        for (int m = 0; m < 4; ++m)
#pragma unroll
            for (int q = 0; q < 4; ++q) {
                int row = wave * 64 + m * 16 + lg * 4 + q;
                op[(size_t)row * HW + n * 16 + lr] = acc[m][n][q] * rc * gg[m][q];
            }
    }
}

extern "C" void kernel_launch(void* const* d_in, const int* in_sizes, int n_in,
                              void* d_out, int out_size, void* d_ws, size_t ws_size,
                              hipStream_t stream) {
    const float* x     = (const float*)d_in[0];
    const float* g1    = (const float*)d_in[1];
    const float* wqkv  = (const float*)d_in[2];
    const float* memkv = (const float*)d_in[3];
    const float* wout  = (const float*)d_in[4];
    const float* bout  = (const float*)d_in[5];
    const float* g2    = (const float*)d_in[6];
    float* out = (float*)d_out;
    char* ws = (char*)d_ws;

    short* w1b  = (short*)(ws + OFF_W1B);
    float* r    = (float*)(ws + OFF_R);
    float* rpart= (float*)(ws + OFF_RP);
    float* pctx = (float*)(ws + OFF_PCTX);
    short* Mmat = (short*)(ws + OFF_M);
    short* qT   = (short*)(ws + OFF_QT);
    short* kv   = (short*)(ws + OFF_KV);
    short* xT   = (short*)(ws + OFF_XT);

    k_prep<<<384, 256, 0, stream>>>(wqkv, g1, w1b);
    k_tr<<<dim3(64, 4, NB), 256, 0, stream>>>(x, xT, rpart);
    k_rfin<<<256, 256, 0, stream>>>(rpart, r);
    k_qkv<<<dim3(32, 3, NB), 256, 0, stream>>>(w1b, xT, r, kv, qT);
    k_ctx<<<dim3(8, 64), 256, 0, stream>>>(kv, pctx);
    k_M<<<dim3(8, NB), 256, 0, stream>>>(pctx, memkv, wout, Mmat);
    k_out2<<<dim3(64, NB), 256, 0, stream>>>(Mmat, qT, bout, g2, out);
}

// Round 5
// 81.198 us; speedup vs baseline: 6.1260x; 1.4682x over previous
//
#include <hip/hip_runtime.h>
#include <hip/hip_bf16.h>

#define NB 16
#define DIM 256
#define HW 4096
#define HEADS 4
#define DHEAD 32
#define MEM 4
#define HIDDEN 128

typedef __hip_bfloat16 bf16;
typedef __attribute__((ext_vector_type(8))) short bf16x8;
typedef __attribute__((ext_vector_type(4))) float f32x4;
typedef __attribute__((ext_vector_type(4))) unsigned short us4;

#define AS1 __attribute__((address_space(1)))
#define AS3 __attribute__((address_space(3)))

__device__ __forceinline__ void gld_lds16(const void* g, void* l) {
    __builtin_amdgcn_global_load_lds((const AS1 void*)g, (AS3 void*)l, 16, 0, 0);
}
__device__ __forceinline__ float b2f(short s) {
    union { unsigned int u; float f; } x; x.u = ((unsigned int)(unsigned short)s) << 16; return x.f;
}
__device__ __forceinline__ short f2bs(float f) {
    bf16 h = __float2bfloat16(f);
    return *reinterpret_cast<short*>(&h);
}

// ---- ws layout (bytes) ----
constexpr size_t OFF_W1B  = 0;                                    // 98304 bf16
constexpr size_t OFF_PCTX = OFF_W1B + 98304*2;                    // 64*64*1056 f32 = 17.3MB
constexpr size_t OFF_CTXN = OFF_PCTX + (size_t)64*64*1056*4;      // 64*1024 f32
constexpr size_t OFF_M    = OFF_CTXN + (size_t)64*1024*4;         // 16*256*128 bf16
constexpr size_t OFF_QT   = OFF_M + (size_t)NB*DIM*HIDDEN*2;      // 16*4096*128 bf16

// K1: w1b = bf16(w_qkv * g1)
__global__ void k_prep(const float* __restrict__ wqkv, const float* __restrict__ g1,
                       short* __restrict__ w1b) {
    int i = blockIdx.x * 256 + threadIdx.x;
    w1b[i] = f2bs(wqkv[i] * g1[i & (DIM - 1)]);
}

// K2 mega-kernel: per (64-col, b) block:
//  x (f32, read once) -> in-LDS transpose+bf16 -> GEMM w1b(384x256) -> per-col RMS r
//  -> q: softmax -> qT;  k,v: exp/scale -> in-LDS bf16 tiles -> PV-MFMA -> pctx partials
__global__ __launch_bounds__(384) void k_fused(const short* __restrict__ w1b,
                                               const float* __restrict__ x,
                                               short* __restrict__ qT,
                                               float* __restrict__ pctx) {
    int nt = blockIdx.x, b = blockIdx.y;
    int n0 = nt * 64;
    __shared__ char smem[65536];
    short* As = (short*)smem;                  // [384][64] bf16, XOR-swizzled (48KB)
    short* Bs = (short*)(smem + 49152);        // [64 n][64 c] bf16, XOR-swizzled (8KB)
    short* xs = (short*)(smem + 57344);        // [64 c][64 n] bf16, linear (8KB)
    int t = threadIdx.x;
    int w = t >> 6, lane = t & 63;
    int lr = lane & 15, lg = lane >> 4;
    const f32x4 fz = {0.f, 0.f, 0.f, 0.f};
    f32x4 acc[4][4];
#pragma unroll
    for (int m = 0; m < 4; ++m)
#pragma unroll
        for (int n = 0; n < 4; ++n) acc[m][n] = fz;
    f32x4 ssv = fz;
    const float* xb = x + (size_t)b * DIM * HW + n0;

    for (int kk = 0; kk < 256; kk += 64) {
        __syncthreads();                        // (A) LDS free of prev MFMA reads
#pragma unroll
        for (int is = 0; is < 8; ++is) {        // A-tile: async global->LDS, swizzled src
            int o = is * 6144 + t * 16;
            int row = o >> 7;
            int js = ((o >> 4) & 7) ^ (row & 7);
            gld_lds16(w1b + (size_t)row * 256 + kk + js * 8, smem + o);
        }
        if (t < 256) {                          // x load (f32) + sumsq + bf16 -> xs[c][n]
            int rr = t >> 4, cc = (t & 15) * 4;
#pragma unroll
            for (int p = 0; p < 4; ++p) {
                int c = rr + p * 16;
                f32x4 v4 = *(const f32x4*)(xb + (size_t)(kk + c) * HW + cc);
                us4 h4;
#pragma unroll
                for (int j = 0; j < 4; ++j) { ssv[j] += v4[j] * v4[j]; h4[j] = (unsigned short)f2bs(v4[j]); }
                *(us4*)(xs + c * 64 + cc) = h4;
            }
        }
        __syncthreads();                        // (B) xs ready
        if (t < 256) {                          // transpose-read -> Bs[n][c] swizzled
            int n = t & 63, cq = t >> 6;
            alignas(16) short tmp[16];
#pragma unroll
            for (int i = 0; i < 16; ++i) tmp[i] = xs[(cq * 16 + i) * 64 + n];
            *(bf16x8*)(Bs + n * 64 + (((cq * 2)     ^ (n & 7)) << 3)) = *(bf16x8*)tmp;
            *(bf16x8*)(Bs + n * 64 + (((cq * 2 + 1) ^ (n & 7)) << 3)) = *(bf16x8*)(tmp + 8);
        }
        __syncthreads();                        // (C) Bs ready + As glds drained
#pragma unroll
        for (int ks = 0; ks < 2; ++ks) {
            bf16x8 av[4], bv[4];
            int j = lg + 4 * ks;
#pragma unroll
            for (int m = 0; m < 4; ++m) {
                int row = w * 64 + m * 16 + lr;
                av[m] = *(const bf16x8*)(As + row * 64 + ((j ^ (row & 7)) << 3));
            }
#pragma unroll
            for (int n = 0; n < 4; ++n) {
                int row = n * 16 + lr;
                bv[n] = *(const bf16x8*)(Bs + row * 64 + ((j ^ (row & 7)) << 3));
            }
#pragma unroll
            for (int m = 0; m < 4; ++m)
#pragma unroll
                for (int n = 0; n < 4; ++n)
                    acc[m][n] = __builtin_amdgcn_mfma_f32_16x16x32_bf16(av[m], bv[n], acc[m][n], 0, 0, 0);
        }
    }
    __syncthreads();                            // GEMM done; LDS reusable
    float* ssp = (float*)(smem + 32768);        // [16][64] f32
    float* r2s = (float*)(smem + 36864);        // [64] f32
    short* ekb = (short*)smem;                  // [128][64] bf16 linear (16KB)
    short* vb  = (short*)(smem + 16384);        // [128][64] bf16 linear (16KB)
    if (t < 256) *(f32x4*)(ssp + (t >> 4) * 64 + (t & 15) * 4) = ssv;
    __syncthreads();
    if (t < 64) {
        float s = 0.f;
#pragma unroll
        for (int g = 0; g < 16; ++g) s += ssp[g * 64 + t];
        r2s[t] = 16.0f / fmaxf(sqrtf(s), 1e-12f);
    }
    __syncthreads();
    float rv[4];
#pragma unroll
    for (int nf = 0; nf < 4; ++nf) rv[nf] = r2s[nf * 16 + lr];

    if (w < 2) {
        // q: softmax over d (32 rows/head), write qT[b][n][hd]
#pragma unroll
        for (int nf = 0; nf < 4; ++nf) {
            int gcol = n0 + nf * 16 + lr;
#pragma unroll
            for (int a = 0; a < 2; ++a) {
                float v[8];
#pragma unroll
                for (int mm = 0; mm < 2; ++mm)
#pragma unroll
                    for (int q = 0; q < 4; ++q)
                        v[mm * 4 + q] = acc[2 * a + mm][nf][q] * rv[nf];
                float mx = v[0];
#pragma unroll
                for (int i = 1; i < 8; ++i) mx = fmaxf(mx, v[i]);
                mx = fmaxf(mx, __shfl_xor(mx, 16));
                mx = fmaxf(mx, __shfl_xor(mx, 32));
                float sum = 0.f;
#pragma unroll
                for (int i = 0; i < 8; ++i) { v[i] = __expf(v[i] - mx); sum += v[i]; }
                sum += __shfl_xor(sum, 16);
                sum += __shfl_xor(sum, 32);
                float inv = 0.17677669529663689f / sum;
                size_t base = ((size_t)b * HW + gcol) * 128 + (w * 2 + a) * 32 + lg * 4;
#pragma unroll
                for (int mm = 0; mm < 2; ++mm) {
                    us4 pk;
#pragma unroll
                    for (int q = 0; q < 4; ++q)
                        pk[q] = (unsigned short)f2bs(v[mm * 4 + q] * inv);
                    *(us4*)(qT + base + mm * 16) = pk;
                }
            }
        }
    } else if (w < 4) {
        // k rows: ek = exp(k*r) -> bf16 tile
#pragma unroll
        for (int m = 0; m < 4; ++m)
#pragma unroll
            for (int nf = 0; nf < 4; ++nf)
#pragma unroll
                for (int q = 0; q < 4; ++q) {
                    int rloc = (w - 2) * 64 + m * 16 + lg * 4 + q;
                    ekb[rloc * 64 + nf * 16 + lr] = f2bs(__expf(acc[m][nf][q] * rv[nf]));
                }
    } else {
        // v rows -> bf16 tile
#pragma unroll
        for (int m = 0; m < 4; ++m)
#pragma unroll
            for (int nf = 0; nf < 4; ++nf)
#pragma unroll
                for (int q = 0; q < 4; ++q) {
                    int rloc = (w - 4) * 64 + m * 16 + lg * 4 + q;
                    vb[rloc * 64 + nf * 16 + lr] = f2bs(acc[m][nf][q] * rv[nf]);
                }
    }
    __syncthreads();
    if (w < 4) {
        // PV MFMA: ctx_h[d][e] = sum_n ek[d][n]*v[e][n]; wave w owns head h=w
        int h = w;
        f32x4 c2[2][2];
        c2[0][0] = fz; c2[0][1] = fz; c2[1][0] = fz; c2[1][1] = fz;
#pragma unroll
        for (int ks = 0; ks < 2; ++ks) {
            int j = lg + 4 * ks;
            bf16x8 a2[2], b2[2];
#pragma unroll
            for (int mm = 0; mm < 2; ++mm)
                a2[mm] = *(const bf16x8*)(ekb + (h * 32 + mm * 16 + lr) * 64 + j * 8);
#pragma unroll
            for (int nn = 0; nn < 2; ++nn)
                b2[nn] = *(const bf16x8*)(vb + (h * 32 + nn * 16 + lr) * 64 + j * 8);
#pragma unroll
            for (int mm = 0; mm < 2; ++mm)
#pragma unroll
                for (int nn = 0; nn < 2; ++nn)
                    c2[mm][nn] = __builtin_amdgcn_mfma_f32_16x16x32_bf16(a2[mm], b2[nn], c2[mm][nn], 0, 0, 0);
        }
        float* o = pctx + ((size_t)nt * 64 + b * 4 + h) * 1056;
#pragma unroll
        for (int mm = 0; mm < 2; ++mm)
#pragma unroll
            for (int nn = 0; nn < 2; ++nn)
#pragma unroll
                for (int qq = 0; qq < 4; ++qq) {
                    int d = mm * 16 + lg * 4 + qq;
                    int e = nn * 16 + lr;
                    o[d * 32 + e] = c2[mm][nn][qq];
                }
    } else {
        // rowsum partials from the same bf16 ek values
        int hd = (w - 4) * 64 + lane;
        float rs = 0.f;
#pragma unroll
        for (int blk = 0; blk < 8; ++blk) {
            bf16x8 e8 = *(const bf16x8*)(ekb + hd * 64 + blk * 8);
#pragma unroll
            for (int j = 0; j < 8; ++j) rs += b2f(e8[j]);
        }
        pctx[((size_t)nt * 64 + b * 4 + (hd >> 5)) * 1056 + 1024 + (hd & 31)] = rs;
    }
}

// K3: reduce pctx over 64 chunks + mem-KV terms + normalize -> ctxn[bh][d*32+e]
__global__ __launch_bounds__(256) void k_red(const float* __restrict__ pctx,
                                             const float* __restrict__ memkv,
                                             float* __restrict__ ctxn) {
    int ds = blockIdx.x, bh = blockIdx.y;
    int t = threadIdx.x;
    int dd = t >> 5, ee = t & 31;
    int d = ds * 8 + dd;
    int h = bh & 3;
    __shared__ float rss[8];
    float s = 0.f;
#pragma unroll 8
    for (int c = 0; c < 64; ++c)
        s += pctx[((size_t)c * 64 + bh) * 1056 + d * 32 + ee];
    if (t < 8) {
        int d2 = ds * 8 + t;
        float rs = 0.f;
#pragma unroll 8
        for (int c = 0; c < 64; ++c)
            rs += pctx[((size_t)c * 64 + bh) * 1056 + 1024 + d2];
#pragma unroll
        for (int m2 = 0; m2 < MEM; ++m2) rs += __expf(memkv[(h * 32 + d2) * MEM + m2]);
        rss[t] = rs;
    }
    float mem = 0.f;
#pragma unroll
    for (int m2 = 0; m2 < MEM; ++m2)
        mem += __expf(memkv[(h * 32 + d) * MEM + m2]) * memkv[512 + (h * 32 + ee) * MEM + m2];
    __syncthreads();
    ctxn[(size_t)bh * 1024 + d * 32 + ee] = (s + mem) / rss[dd];
}

// K4: fold w_out: Mmat[b][o][hd] = sum_e wout[o][h*32+e] * ctxn[b*4+h][d][e]
__global__ __launch_bounds__(256) void k_M2(const float* __restrict__ ctxn,
                                            const float* __restrict__ wout,
                                            short* __restrict__ Mmat) {
    int og = blockIdx.x, b = blockIdx.y;
    __shared__ float ctx[4 * 33 * 33];
    __shared__ float wsw[32 * 136];
    int t = threadIdx.x;
#pragma unroll
    for (int j = 0; j < 16; ++j) {
        int e = t + j * 256;
        int h = e >> 10, dd = (e >> 5) & 31, ee = e & 31;
        ctx[h * 1089 + dd * 33 + ee] = ctxn[(size_t)(b * 4 + h) * 1024 + (e & 1023)];
    }
#pragma unroll
    for (int j = 0; j < 4; ++j) {
        int e4 = t + j * 256;
        int row = e4 >> 5, c = (e4 & 31) * 4;
        f32x4 w4 = *(const f32x4*)(wout + (size_t)(og * 32 + row) * HIDDEN + c);
        *(f32x4*)(wsw + row * 136 + (c >> 5) * 34 + (c & 31)) = w4;
    }
    __syncthreads();
    int ol = t >> 3, hg = t & 7;
    alignas(16) short out16[16];
#pragma unroll
    for (int ii = 0; ii < 16; ++ii) {
        int hd = hg * 16 + ii;
        int h = hd >> 5, dd = hd & 31;
        float s = 0.f;
#pragma unroll
        for (int e = 0; e < 32; ++e)
            s += wsw[ol * 136 + h * 34 + e] * ctx[h * 1089 + dd * 33 + e];
        out16[ii] = f2bs(s);
    }
    short* op = Mmat + ((size_t)(b * 256 + og * 32 + ol)) * 128 + hg * 16;
    *(bf16x8*)(op)     = *(bf16x8*)(out16);
    *(bf16x8*)(op + 8) = *(bf16x8*)(out16 + 8);
}

// K5: fused final GEMM + bias + column RMS-norm + g2 scale -> f32 out
__global__ __launch_bounds__(256) void k_out2(const short* __restrict__ Mmat,
                                              const short* __restrict__ qT,
                                              const float* __restrict__ bout,
                                              const float* __restrict__ g2,
                                              float* __restrict__ out) {
    int nt = blockIdx.x, b = blockIdx.y;
    __shared__ short As[256 * 64];
    __shared__ short Bs[64 * 64];
    __shared__ float sw[4][80];
    __shared__ float r2s[64];
    int t = threadIdx.x;
    int wave = t >> 6, lane = t & 63;
    int lr = lane & 15, lg = lane >> 4;
    const short* Ag = Mmat + (size_t)b * 256 * 128;
    const short* Bg = qT + ((size_t)b * HW + nt * 64) * 128;
    const f32x4 fz = {0.f, 0.f, 0.f, 0.f};
    f32x4 acc[4][4];
#pragma unroll
    for (int m = 0; m < 4; ++m)
#pragma unroll
        for (int n = 0; n < 4; ++n) acc[m][n] = fz;

    for (int kk = 0; kk < 128; kk += 64) {
        if (kk) __syncthreads();
#pragma unroll
        for (int is = 0; is < 8; ++is) {
            int o = is * 4096 + t * 16;
            int rr2 = o >> 7;
            int js = ((o >> 4) & 7) ^ (rr2 & 7);
            gld_lds16(Ag + (size_t)rr2 * 128 + kk + js * 8, (char*)As + o);
        }
#pragma unroll
        for (int is = 0; is < 2; ++is) {
            int o = is * 4096 + t * 16;
            int rr2 = o >> 7;
            int js = ((o >> 4) & 7) ^ (rr2 & 7);
            gld_lds16(Bg + (size_t)rr2 * 128 + kk + js * 8, (char*)Bs + o);
        }
        __syncthreads();
#pragma unroll
        for (int ks = 0; ks < 2; ++ks) {
            bf16x8 av[4], bv[4];
            int j = lg + 4 * ks;
#pragma unroll
            for (int m = 0; m < 4; ++m) {
                int row = wave * 64 + m * 16 + lr;
                av[m] = *(const bf16x8*)((const char*)As + row * 128 + ((j ^ (row & 7)) << 4));
            }
#pragma unroll
            for (int n = 0; n < 4; ++n) {
                int row = n * 16 + lr;
                bv[n] = *(const bf16x8*)((const char*)Bs + row * 128 + ((j ^ (row & 7)) << 4));
            }
#pragma unroll
            for (int m = 0; m < 4; ++m)
#pragma unroll
                for (int n = 0; n < 4; ++n)
                    acc[m][n] = __builtin_amdgcn_mfma_f32_16x16x32_bf16(av[m], bv[n], acc[m][n], 0, 0, 0);
        }
    }
    float bb[4][4], gg[4][4];
#pragma unroll
    for (int m = 0; m < 4; ++m)
#pragma unroll
        for (int q = 0; q < 4; ++q) {
            int row = wave * 64 + m * 16 + lg * 4 + q;
            bb[m][q] = bout[row];
            gg[m][q] = g2[row];
        }
    float ssn[4] = {0.f, 0.f, 0.f, 0.f};
#pragma unroll
    for (int n = 0; n < 4; ++n)
#pragma unroll
        for (int m = 0; m < 4; ++m)
#pragma unroll
            for (int q = 0; q < 4; ++q) {
                float val = acc[m][n][q] + bb[m][q];
                acc[m][n][q] = val;
                ssn[n] += val * val;
            }
#pragma unroll
    for (int n = 0; n < 4; ++n) {
        ssn[n] += __shfl_xor(ssn[n], 16);
        ssn[n] += __shfl_xor(ssn[n], 32);
    }
    if (lg == 0) {
#pragma unroll
        for (int n = 0; n < 4; ++n) sw[wave][n * 16 + lr] = ssn[n];
    }
    __syncthreads();
    if (t < 64) {
        float s = sw[0][t] + sw[1][t] + sw[2][t] + sw[3][t];
        r2s[t] = 16.0f / fmaxf(sqrtf(s), 1e-12f);
    }
    __syncthreads();
    float* op = out + (size_t)b * DIM * HW + nt * 64;
#pragma unroll
    for (int n = 0; n < 4; ++n) {
        float rc = r2s[n * 16 + lr];
#pragma unroll
        for (int m = 0; m < 4; ++m)
#pragma unroll
            for (int q = 0; q < 4; ++q) {
                int row = wave * 64 + m * 16 + lg * 4 + q;
                op[(size_t)row * HW + n * 16 + lr] = acc[m][n][q] * rc * gg[m][q];
            }
    }
}

extern "C" void kernel_launch(void* const* d_in, const int* in_sizes, int n_in,
                              void* d_out, int out_size, void* d_ws, size_t ws_size,
                              hipStream_t stream) {
    const float* x     = (const float*)d_in[0];
    const float* g1    = (const float*)d_in[1];
    const float* wqkv  = (const float*)d_in[2];
    const float* memkv = (const float*)d_in[3];
    const float* wout  = (const float*)d_in[4];
    const float* bout  = (const float*)d_in[5];
    const float* g2    = (const float*)d_in[6];
    float* out = (float*)d_out;
    char* ws = (char*)d_ws;

    short* w1b  = (short*)(ws + OFF_W1B);
    float* pctx = (float*)(ws + OFF_PCTX);
    float* ctxn = (float*)(ws + OFF_CTXN);
    short* Mmat = (short*)(ws + OFF_M);
    short* qT   = (short*)(ws + OFF_QT);

    k_prep<<<384, 256, 0, stream>>>(wqkv, g1, w1b);
    k_fused<<<dim3(64, NB), 384, 0, stream>>>(w1b, x, qT, pctx);
    k_red<<<dim3(4, 64), 256, 0, stream>>>(pctx, memkv, ctxn);
    k_M2<<<dim3(8, NB), 256, 0, stream>>>(ctxn, wout, Mmat);
    k_out2<<<dim3(64, NB), 256, 0, stream>>>(Mmat, qT, bout, g2, out);
}